// Round 3
// baseline (1051.800 us; speedup 1.0000x reference)
//
#include <hip/hip_runtime.h>
#include <hip/hip_bf16.h>
#include <math.h>

// ---------------- constants (problem is fixed-shape) ----------------
// B=2, H=W=256, L=65536, C=180, NH=6, hd=30, WS=8, hd_ffn=360
// I/O dtype: fp32 (per reference). Internals: bf16 (MFMA), fp32 accum.
#define BATCH 2
#define IMG 256
#define LTOK 65536
#define CH 180
#define BL (BATCH * LTOK)            // 131072 tokens
#define HDF 360

using frag_ab = __attribute__((ext_vector_type(8))) short;   // 8 bf16 in 4 VGPRs
using frag_cd = __attribute__((ext_vector_type(4))) float;   // 4 f32 acc

__device__ __forceinline__ float b2f(unsigned short u) {
    union { unsigned int i; float f; } v; v.i = ((unsigned int)u) << 16; return v.f;
}
__device__ __forceinline__ float blo(unsigned int u) {
    union { unsigned int i; float f; } v; v.i = u << 16; return v.f;
}
__device__ __forceinline__ float bhi(unsigned int u) {
    union { unsigned int i; float f; } v; v.i = u & 0xffff0000u; return v.f;
}
__device__ __forceinline__ unsigned short f2b(float f) {
    union { float f; unsigned int i; } v; v.f = f;
    unsigned int x = v.i;
    unsigned int r = (x + 0x7fffu + ((x >> 16) & 1u)) >> 16;   // RNE
    return (unsigned short)r;
}
__device__ __forceinline__ float gelu_f(float x) {
    return 0.5f * x * (1.0f + erff(x * 0.70710678118654752f));
}

// row-index permutations for window attention, folded into GEMM epilogues.
// PERM=1: token-order row -> window-order position. PERM=2: inverse.
template <int PERM>
__device__ __forceinline__ int perm_row(int row) {
    if (PERM == 1) {
        int b = row >> 16, l = row & 65535;
        int y = l >> 8, x = l & 255;
        return (b << 16) + ((((y >> 3) << 5) + (x >> 3)) << 6) + ((y & 7) << 3) + (x & 7);
    } else if (PERM == 2) {
        int b = row >> 16, wv = row & 65535;
        int wid = wv >> 6, t = wv & 63;
        int wy = wid >> 5, wx = wid & 31;
        return (b << 16) + ((((wy << 3) + (t >> 3))) << 8) + (wx << 3) + (t & 7);
    }
    return row;
}

// ---------------- one-shot weight prep ----------------
// wbf: bf16 copies of the 4 GEMM weights. wT1/wT2: tap-major dwconv weights.
// br3: b_rel re-ordered to MFMA fragment order per (head, lane):
//      br3[h*4096 + lane*64 + (mt*16+nt*4+r)] = bf16(b_rel[h][mt*16+(lane>>4)*4+r][nt*16+(lane&15)])
__global__ __launch_bounds__(256) void convw_kernel(
    const float* __restrict__ a, const float* __restrict__ b,
    const float* __restrict__ c, const float* __restrict__ d,
    const float* __restrict__ cdw, const float* __restrict__ fdw,
    const float* __restrict__ brel,
    unsigned short* __restrict__ wbf, float* __restrict__ wT1, float* __restrict__ wT2,
    unsigned short* __restrict__ br3)
{
    int g = blockIdx.x * 256 + threadIdx.x;
    if (g < 259200) {
        float v;
        if      (g < 97200)  v = a[g];
        else if (g < 129600) v = b[g - 97200];
        else if (g < 194400) v = c[g - 129600];
        else                 v = d[g - 194400];
        wbf[g] = f2b(v);
    } else if (g < 265680) {
        int i = g - 259200;               // tap-major [9][180]
        int tap = i / 180, ch = i % 180;
        wT1[i] = cdw[ch * 9 + tap];
    } else if (g < 278640) {
        int i = g - 265680;               // [9][360]
        int tap = i / 360, ch = i % 360;
        wT2[i] = fdw[ch * 9 + tap];
    } else if (g < 303216) {
        int i = g - 278640;               // 6*4096 fragment-ordered bias
        int h = i >> 12;
        int rem = i & 4095;
        int lane = rem >> 6;
        int j = rem & 63;
        int mt = j >> 4, nt = (j >> 2) & 3, r = j & 3;
        int row = mt * 16 + (lane >> 4) * 4 + r;
        int col = nt * 16 + (lane & 15);
        br3[i] = f2b(brel[h * 4096 + row * 64 + col]);
    }
}

// ---------------- LayerNorm: one wave per token, vectorized (45 active lanes) ----------------
__device__ __forceinline__ void ld4(const float* p, float v[4]) {
    float4 t = *(const float4*)p; v[0]=t.x; v[1]=t.y; v[2]=t.z; v[3]=t.w;
}
__device__ __forceinline__ void ld4(const unsigned short* p, float v[4]) {
    ushort4 t = *(const ushort4*)p; v[0]=b2f(t.x); v[1]=b2f(t.y); v[2]=b2f(t.z); v[3]=b2f(t.w);
}

template <typename TIN>
__global__ __launch_bounds__(256) void ln_kernel(
    const TIN* __restrict__ x, const float* __restrict__ g,
    const float* __restrict__ bta, unsigned short* __restrict__ out)
{
    int wave = threadIdx.x >> 6, lane = threadIdx.x & 63;
    int tok = blockIdx.x * 4 + wave;
    const bool act = lane < 45;                 // 45*4 = 180 channels
    float v[4] = {0.f, 0.f, 0.f, 0.f};
    const TIN* row = x + (size_t)tok * CH;
    if (act) ld4(row + lane * 4, v);
    float s  = v[0] + v[1] + v[2] + v[3];
    float sq = v[0]*v[0] + v[1]*v[1] + v[2]*v[2] + v[3]*v[3];
    #pragma unroll
    for (int off = 32; off > 0; off >>= 1) {
        s  += __shfl_xor(s, off);
        sq += __shfl_xor(sq, off);
    }
    float mean = s * (1.f / CH);
    float var  = sq * (1.f / CH) - mean * mean;
    float rstd = rsqrtf(var + 1e-5f);
    if (act) {
        float4 gg = *(const float4*)&g[lane * 4];
        float4 bb = *(const float4*)&bta[lane * 4];
        unsigned int o0 = (unsigned int)f2b((v[0]-mean)*rstd*gg.x + bb.x)
                        | ((unsigned int)f2b((v[1]-mean)*rstd*gg.y + bb.y) << 16);
        unsigned int o1 = (unsigned int)f2b((v[2]-mean)*rstd*gg.z + bb.z)
                        | ((unsigned int)f2b((v[3]-mean)*rstd*gg.w + bb.w) << 16);
        *(uint2*)(out + (size_t)tok * CH + lane * 4) = make_uint2(o0, o1);
    }
}

// ---------------- generic MFMA GEMM, 256x64 tile (+ optional row-perm epilogue) ----------------
// Grid: (n_tiles, BL/256) -- n fastest so blocks sharing an A-panel dispatch together (L2/L3 reuse).
// 4 waves; wave w owns rows [w*64, w*64+64) x all 64 cols: 4x4 fragment acc = 64 MFMA per
// block K-step between one barrier pair (4x the old 64x64 tile's amortization).
__device__ __forceinline__ void stv(float* p, float v) { *p = v; }
__device__ __forceinline__ void stv(unsigned short* p, float v) { *p = f2b(v); }

template <int ACT, bool HAS_BIAS, bool HAS_RES, int PERM, typename TOUT>
__global__ __launch_bounds__(256) void gemm_kernel(
    const unsigned short* __restrict__ X, int ldx,
    const unsigned short* __restrict__ Wt,
    const float* __restrict__ bias,
    const unsigned short* __restrict__ res, int ldr,
    TOUT* __restrict__ Y, int ldy,
    int N, int K)
{
    __shared__ unsigned short Xs[256][40];   // 20480 B, row stride 80 B
    __shared__ unsigned short Ws[64][40];    //  5120 B
    const int tid = threadIdx.x;
    const int wave = tid >> 6;
    const int lane = tid & 63;
    const int l16 = lane & 15;
    const int q = lane >> 4;
    const int n0 = blockIdx.x * 64;
    const int m0 = blockIdx.y * 256;
    const int lr = tid >> 2;                 // 0..63
    const int lk = (tid & 3) << 3;           // 0,8,16,24

    frag_cd acc[4][4];
    #pragma unroll
    for (int mb = 0; mb < 4; ++mb)
        #pragma unroll
        for (int nb = 0; nb < 4; ++nb)
            acc[mb][nb] = (frag_cd){0.f, 0.f, 0.f, 0.f};

    for (int k0 = 0; k0 < K; k0 += 32) {
        const bool kfull = (k0 + 32 <= K);
        // ---- stage A: 4 sub-rounds, thread covers row rr*64+lr, 8 shorts at lk ----
        #pragma unroll
        for (int rr = 0; rr < 4; ++rr) {
            const int row = rr * 64 + lr;
            const unsigned short* p = X + (size_t)(m0 + row) * ldx + (k0 + lk);
            if (kfull) {
                uint2 u0 = *(const uint2*)p;
                uint2 u1 = *(const uint2*)(p + 4);
                *(uint4*)&Xs[row][lk] = make_uint4(u0.x, u0.y, u1.x, u1.y);
            } else {
                #pragma unroll
                for (int j = 0; j < 8; ++j)
                    Xs[row][lk + j] = (k0 + lk + j < K) ? p[j] : (unsigned short)0;
            }
        }
        // ---- stage B: row lr (n), 8 shorts at lk ----
        {
            const int n = n0 + lr;
            const unsigned short* p = Wt + (size_t)n * K + (k0 + lk);
            if (n < N && kfull) {
                uint2 u0 = *(const uint2*)p;
                uint2 u1 = *(const uint2*)(p + 4);
                *(uint4*)&Ws[lr][lk] = make_uint4(u0.x, u0.y, u1.x, u1.y);
            } else {
                #pragma unroll
                for (int j = 0; j < 8; ++j)
                    Ws[lr][lk + j] = (n < N && (k0 + lk + j) < K) ? p[j] : (unsigned short)0;
            }
        }
        __syncthreads();
        frag_ab bfr[4];
        #pragma unroll
        for (int nb = 0; nb < 4; ++nb)
            bfr[nb] = *(const frag_ab*)&Ws[nb * 16 + l16][q * 8];
        #pragma unroll
        for (int mb = 0; mb < 4; ++mb) {
            frag_ab afr = *(const frag_ab*)&Xs[wave * 64 + mb * 16 + l16][q * 8];
            #pragma unroll
            for (int nb = 0; nb < 4; ++nb)
                acc[mb][nb] = __builtin_amdgcn_mfma_f32_16x16x32_bf16(afr, bfr[nb], acc[mb][nb], 0, 0, 0);
        }
        __syncthreads();
    }
    #pragma unroll
    for (int nb = 0; nb < 4; ++nb) {
        const int col = n0 + nb * 16 + l16;
        if (col < N) {
            float bv = 0.f;
            if (HAS_BIAS) bv = bias[col];
            #pragma unroll
            for (int mb = 0; mb < 4; ++mb) {
                #pragma unroll
                for (int r = 0; r < 4; ++r) {
                    int row = m0 + wave * 64 + mb * 16 + q * 4 + r;
                    int orow = perm_row<PERM>(row);
                    float v = acc[mb][nb][r] + bv;
                    if (ACT == 1) v = gelu_f(v);
                    if (HAS_RES) v += b2f(res[(size_t)orow * ldr + col]);
                    stv(&Y[(size_t)orow * ldy + col], v);
                }
            }
        }
    }
}

// ---------------- window attention: MFMA, one wave per (window, head) ----------------
// qkvw is WINDOW-ORDERED: row w64 = w*64 + t, cols [q:h*30+d][k:180+...][v:360+...]
// S = Q@K^T via mfma_f32_16x16x32_bf16 (A=[m][k] row-chunk pattern, B=[n][k]);
// C/D layout: col=lane&15, row=(lane>>4)*4+reg  (same convention as gemm_kernel).
// Softmax: per-row max/sum via in-register nt-reduce + shfl_xor(1,2,4,8) over the
// 16-lane column group. P (unnormalized bf16) -> LDS; V staged transposed into LDS
// so the PV B-operand is a linear ds_read_b128. 1/sum folded into the O epilogue.
__global__ __launch_bounds__(64) void attn_kernel(
    const unsigned short* __restrict__ qkvw,
    const unsigned short* __restrict__ br3,
    unsigned short* __restrict__ attn_out)
{
    __shared__ unsigned short Pl[64][72];   // P bf16, stride 72 (144 B: 16B-aligned, 2-way banks)
    __shared__ unsigned short VT[32][72];   // V^T bf16 [d][key], rows 30,31 zeroed
    const int blk = blockIdx.x;             // 0..12287
    const int h = blk % 6;
    const int w = blk / 6;
    const int lane = threadIdx.x;
    const int l16 = lane & 15;
    const int g4 = lane >> 4;
    const float scale = 0.18257418583505536f;  // 30^-0.5

    const unsigned short* base = qkvw + (size_t)w * (64 * 540) + h * 30;

    // ---- Q (A) and K (B) fragments straight from global (4B-aligned uint2 loads) ----
    frag_ab qf[4], kf[4];
    #pragma unroll
    for (int t = 0; t < 4; ++t) {
        const unsigned short* pq = base + (size_t)(t * 16 + l16) * 540 + g4 * 8;
        union { frag_ab f; uint2 u[2]; } tq, tk;
        tq.u[0] = *(const uint2*)pq;        tq.u[1] = *(const uint2*)(pq + 4);
        tk.u[0] = *(const uint2*)(pq + 180); tk.u[1] = *(const uint2*)(pq + 184);
        if (g4 == 3) { tk.f[6] = 0; tk.f[7] = 0; }   // zero K pad cols d=30,31
        qf[t] = tq.f; kf[t] = tk.f;
    }

    // ---- fragment-ordered bias (bf16, coalesced uint4 loads) ----
    unsigned int brw[32];
    {
        const unsigned short* bp = br3 + ((size_t)h << 12) + lane * 64;
        #pragma unroll
        for (int c2 = 0; c2 < 8; ++c2)
            *(uint4*)&brw[c2 * 4] = *(const uint4*)(bp + c2 * 8);
    }

    // ---- S = Q @ K^T : 16 MFMA ----
    frag_cd s[4][4];
    #pragma unroll
    for (int mt = 0; mt < 4; ++mt)
        #pragma unroll
        for (int nt = 0; nt < 4; ++nt)
            s[mt][nt] = (frag_cd){0.f, 0.f, 0.f, 0.f};
    #pragma unroll
    for (int mt = 0; mt < 4; ++mt)
        #pragma unroll
        for (int nt = 0; nt < 4; ++nt)
            s[mt][nt] = __builtin_amdgcn_mfma_f32_16x16x32_bf16(qf[mt], kf[nt], s[mt][nt], 0, 0, 0);

    // ---- stage V^T into LDS (overlaps with MFMA latency) ----
    {
        const unsigned short* pv = base + (size_t)lane * 540 + 360;
        #pragma unroll
        for (int d2 = 0; d2 < 15; ++d2) {
            unsigned int u = *(const unsigned int*)(pv + 2 * d2);
            VT[2 * d2][lane]     = (unsigned short)(u & 0xffffu);
            VT[2 * d2 + 1][lane] = (unsigned short)(u >> 16);
        }
        VT[30][lane] = 0; VT[31][lane] = 0;
    }

    // ---- bias + row softmax (unnormalized P -> LDS), inv kept per (mt,reg) ----
    float inv[4][4];
    #pragma unroll
    for (int mt = 0; mt < 4; ++mt) {
        #pragma unroll
        for (int r = 0; r < 4; ++r) {
            float a0 = s[mt][0][r] * scale + (((0 * 4 + r) & 1) ? bhi(brw[(mt * 16 + 0 + r) >> 1]) : blo(brw[(mt * 16 + 0 + r) >> 1]));
            float a1 = s[mt][1][r] * scale + (((1 * 4 + r) & 1) ? bhi(brw[(mt * 16 + 4 + r) >> 1]) : blo(brw[(mt * 16 + 4 + r) >> 1]));
            float a2 = s[mt][2][r] * scale + (((2 * 4 + r) & 1) ? bhi(brw[(mt * 16 + 8 + r) >> 1]) : blo(brw[(mt * 16 + 8 + r) >> 1]));
            float a3 = s[mt][3][r] * scale + (((3 * 4 + r) & 1) ? bhi(brw[(mt * 16 + 12 + r) >> 1]) : blo(brw[(mt * 16 + 12 + r) >> 1]));
            float m = fmaxf(fmaxf(a0, a1), fmaxf(a2, a3));
            m = fmaxf(m, __shfl_xor(m, 1));
            m = fmaxf(m, __shfl_xor(m, 2));
            m = fmaxf(m, __shfl_xor(m, 4));
            m = fmaxf(m, __shfl_xor(m, 8));
            float e0 = __expf(a0 - m), e1 = __expf(a1 - m);
            float e2 = __expf(a2 - m), e3 = __expf(a3 - m);
            float sum = e0 + e1 + e2 + e3;
            sum += __shfl_xor(sum, 1);
            sum += __shfl_xor(sum, 2);
            sum += __shfl_xor(sum, 4);
            sum += __shfl_xor(sum, 8);
            inv[mt][r] = 1.f / sum;
            int row = mt * 16 + g4 * 4 + r;
            Pl[row][l16]      = f2b(e0);
            Pl[row][16 + l16] = f2b(e1);
            Pl[row][32 + l16] = f2b(e2);
            Pl[row][48 + l16] = f2b(e3);
        }
    }
    __syncthreads();

    // ---- O = P @ V : A-frags from Pl, B-frags from VT, 16 MFMA ----
    frag_ab pf[4][2];
    #pragma unroll
    for (int mt = 0; mt < 4; ++mt)
        #pragma unroll
        for (int kt = 0; kt < 2; ++kt)
            pf[mt][kt] = *(const frag_ab*)&Pl[mt * 16 + l16][kt * 32 + g4 * 8];
    frag_ab vf[2][2];
    #pragma unroll
    for (int nt = 0; nt < 2; ++nt)
        #pragma unroll
        for (int kt = 0; kt < 2; ++kt)
            vf[nt][kt] = *(const frag_ab*)&VT[nt * 16 + l16][kt * 32 + g4 * 8];

    frag_cd o[4][2];
    #pragma unroll
    for (int mt = 0; mt < 4; ++mt)
        #pragma unroll
        for (int nt = 0; nt < 2; ++nt)
            o[mt][nt] = (frag_cd){0.f, 0.f, 0.f, 0.f};
    #pragma unroll
    for (int mt = 0; mt < 4; ++mt)
        #pragma unroll
        for (int nt = 0; nt < 2; ++nt)
            #pragma unroll
            for (int kt = 0; kt < 2; ++kt)
                o[mt][nt] = __builtin_amdgcn_mfma_f32_16x16x32_bf16(pf[mt][kt], vf[nt][kt], o[mt][nt], 0, 0, 0);

    // ---- epilogue: normalize rows by inv, store bf16 (cols 30,31 dropped) ----
    unsigned short* ob = attn_out + (size_t)w * (64 * CH) + h * 30;
    #pragma unroll
    for (int mt = 0; mt < 4; ++mt) {
        #pragma unroll
        for (int r = 0; r < 4; ++r) {
            int row = mt * 16 + g4 * 4 + r;
            float iv = inv[mt][r];
            unsigned short* op = ob + (size_t)row * CH;
            op[l16] = f2b(o[mt][0][r] * iv);
            if (l16 < 14) op[16 + l16] = f2b(o[mt][1][r] * iv);
        }
    }
}

// ---------------- depthwise 3x3 SAME conv, vectorized column-walk ----------------
template <int C, bool DO_GELU>
__global__ __launch_bounds__(256) void dwconv_kernel(
    const unsigned short* __restrict__ in, const float* __restrict__ wT,
    unsigned short* __restrict__ out)
{
    constexpr int NG = (C + 7) / 8;
    constexpr int TY = 8;
    int gid = blockIdx.x * 256 + threadIdx.x;
    int cg = gid % NG;
    int t  = gid / NG;
    int x  = t % IMG;
    int t2 = t / IMG;
    int yb = t2 & 31;
    int bi = t2 >> 5;
    if (bi >= BATCH) return;
    const int c0 = cg * 8;
    const int y0 = yb * TY;

    float w9[9][8];
    #pragma unroll
    for (int tp = 0; tp < 9; ++tp) {
        float4 wa = *(const float4*)&wT[tp * C + c0];
        float4 wb = *(const float4*)&wT[tp * C + c0 + 4];
        w9[tp][0]=wa.x; w9[tp][1]=wa.y; w9[tp][2]=wa.z; w9[tp][3]=wa.w;
        w9[tp][4]=wb.x; w9[tp][5]=wb.y; w9[tp][6]=wb.z; w9[tp][7]=wb.w;
    }

    unsigned int rr[3][3][4];

    auto load_row = [&](int y, unsigned int dst[3][4]) {
        if ((unsigned)y >= (unsigned)IMG) {
            #pragma unroll
            for (int cc = 0; cc < 3; ++cc)
                #pragma unroll
                for (int k = 0; k < 4; ++k) dst[cc][k] = 0u;
            return;
        }
        size_t base = ((size_t)((bi << 16) + (y << 8) + x)) * C + c0;
        #pragma unroll
        for (int cc = 0; cc < 3; ++cc) {
            int xx = x + cc - 1;
            if ((unsigned)xx >= (unsigned)IMG) {
                dst[cc][0] = dst[cc][1] = dst[cc][2] = dst[cc][3] = 0u;
                continue;
            }
            const unsigned short* p = in + base + (ptrdiff_t)(cc - 1) * C;
            uint2 u0 = *(const uint2*)p;
            uint2 u1 = *(const uint2*)(p + 4);
            dst[cc][0] = u0.x; dst[cc][1] = u0.y; dst[cc][2] = u1.x; dst[cc][3] = u1.y;
        }
    };

    load_row(y0 - 1, rr[0]);
    load_row(y0,     rr[1]);

    #pragma unroll
    for (int dy = 0; dy < TY; ++dy) {
        load_row(y0 + dy + 1, rr[(dy + 2) % 3]);
        float acc[8];
        #pragma unroll
        for (int j = 0; j < 8; ++j) acc[j] = 0.f;
        #pragma unroll
        for (int ky = 0; ky < 3; ++ky) {
            unsigned int (*row)[4] = rr[(dy + ky) % 3];
            #pragma unroll
            for (int kx = 0; kx < 3; ++kx) {
                const float* wp = w9[ky * 3 + kx];
                const unsigned int* u = row[kx];
                acc[0] += blo(u[0]) * wp[0];
                acc[1] += bhi(u[0]) * wp[1];
                acc[2] += blo(u[1]) * wp[2];
                acc[3] += bhi(u[1]) * wp[3];
                acc[4] += blo(u[2]) * wp[4];
                acc[5] += bhi(u[2]) * wp[5];
                acc[6] += blo(u[3]) * wp[6];
                acc[7] += bhi(u[3]) * wp[7];
            }
        }
        if (DO_GELU) {
            #pragma unroll
            for (int j = 0; j < 8; ++j) acc[j] = gelu_f(acc[j]);
        }
        size_t ob = ((size_t)((bi << 16) + ((y0 + dy) << 8) + x)) * C + c0;
        unsigned int o0 = (unsigned int)f2b(acc[0]) | ((unsigned int)f2b(acc[1]) << 16);
        unsigned int o1 = (unsigned int)f2b(acc[2]) | ((unsigned int)f2b(acc[3]) << 16);
        *(uint2*)(out + ob) = make_uint2(o0, o1);
        if (c0 + 8 <= C) {
            unsigned int o2 = (unsigned int)f2b(acc[4]) | ((unsigned int)f2b(acc[5]) << 16);
            unsigned int o3 = (unsigned int)f2b(acc[6]) | ((unsigned int)f2b(acc[7]) << 16);
            *(uint2*)(out + ob + 4) = make_uint2(o2, o3);
        }
    }
}

// ---------------- sum-pool over L per (b,c), ushort4 ----------------
__global__ __launch_bounds__(64) void pool_kernel(
    const unsigned short* __restrict__ cf, float* __restrict__ pooled)
{
    int t = threadIdx.x;
    if (t >= 45) return;
    int b = blockIdx.x >> 7;
    int chunk = blockIdx.x & 127;
    const unsigned short* base = cf + (size_t)(b * LTOK + chunk * 512) * CH + t * 4;
    float s0 = 0.f, s1 = 0.f, s2 = 0.f, s3 = 0.f;
    for (int i = 0; i < 512; ++i) {
        ushort4 v = *(const ushort4*)(base + (size_t)i * CH);
        s0 += b2f(v.x); s1 += b2f(v.y); s2 += b2f(v.z); s3 += b2f(v.w);
    }
    atomicAdd(&pooled[b * CH + t * 4 + 0], s0);
    atomicAdd(&pooled[b * CH + t * 4 + 1], s1);
    atomicAdd(&pooled[b * CH + t * 4 + 2], s2);
    atomicAdd(&pooled[b * CH + t * 4 + 3], s3);
}

// ---------------- channel gate ----------------
__global__ __launch_bounds__(256) void cm_kernel(
    const float* __restrict__ pooled, const float* __restrict__ w1,
    const float* __restrict__ w2, float* __restrict__ cm)
{
    __shared__ float p[BATCH][CH];
    __shared__ float g1[BATCH][22];
    int t = threadIdx.x;
    for (int idx = t; idx < BATCH * CH; idx += 256)
        p[idx / CH][idx % CH] = pooled[idx] * (1.f / (float)LTOK);
    __syncthreads();
    if (t < BATCH * 22) {
        int b = t / 22, u = t % 22;
        float s = 0.f;
        for (int c = 0; c < CH; ++c) s += p[b][c] * w1[u * CH + c];
        g1[b][u] = gelu_f(s);
    }
    __syncthreads();
    for (int idx = t; idx < BATCH * CH; idx += 256) {
        int b = idx / CH, c = idx % CH;
        float s = 0.f;
        for (int u = 0; u < 22; ++u) s += g1[b][u] * w2[c * 22 + u];
        cm[idx] = 1.f / (1.f + __expf(-s));
    }
}

// ---------------- residual 1, 4 channels/thread ----------------
__global__ __launch_bounds__(256) void resid_kernel(
    const float* __restrict__ x, const unsigned short* __restrict__ attn_feat,
    const unsigned short* __restrict__ conv_feat, const float* __restrict__ cm,
    unsigned short* __restrict__ x_mid)
{
    int gid = blockIdx.x * 256 + threadIdx.x;     // BL*CH/4 threads
    int c4 = gid % 45;
    int b = gid / (LTOK * 45);
    float4 xv = ((const float4*)x)[gid];
    ushort4 a = ((const ushort4*)attn_feat)[gid];
    ushort4 c = ((const ushort4*)conv_feat)[gid];
    float4 m = *(const float4*)&cm[b * CH + c4 * 4];
    unsigned int o0 = (unsigned int)f2b(xv.x + b2f(a.x) * m.x + b2f(c.x))
                    | ((unsigned int)f2b(xv.y + b2f(a.y) * m.y + b2f(c.y)) << 16);
    unsigned int o1 = (unsigned int)f2b(xv.z + b2f(a.z) * m.z + b2f(c.z))
                    | ((unsigned int)f2b(xv.w + b2f(a.w) * m.w + b2f(c.w)) << 16);
    ((uint2*)x_mid)[gid] = make_uint2(o0, o1);
}

// ---------------- launch ----------------
extern "C" void kernel_launch(void* const* d_in, const int* in_sizes, int n_in,
                              void* d_out, int out_size, void* d_ws, size_t ws_size,
                              hipStream_t stream)
{
    const float* x       = (const float*)d_in[0];
    const float* w_qkv   = (const float*)d_in[1];
    const float* b_rel   = (const float*)d_in[2];
    const float* w_proj  = (const float*)d_in[3];
    const float* b_proj  = (const float*)d_in[4];
    const float* conv_dw = (const float*)d_in[5];
    const float* cg_w1   = (const float*)d_in[6];
    const float* cg_w2   = (const float*)d_in[7];
    const float* ffn_w1  = (const float*)d_in[8];
    const float* ffn_dw  = (const float*)d_in[9];
    const float* ffn_w2  = (const float*)d_in[10];
    const float* n1_g    = (const float*)d_in[11];
    const float* n1_b    = (const float*)d_in[12];
    const float* n2_g    = (const float*)d_in[13];
    const float* n2_b    = (const float*)d_in[14];

    // ---- workspace layout (bytes), peak ~225.7 MiB ----
    char* ws = (char*)d_ws;
    unsigned short* n1        = (unsigned short*)(ws);                      // [0, 47.2MB)
    unsigned short* qkvw      = (unsigned short*)(ws + 47185920);           // [47.2, 188.7MB) window-ordered
    unsigned short* conv_feat = (unsigned short*)(ws + 188743680);          // [188.7, 235.9MB)
    unsigned short* attn_out  = (unsigned short*)(ws);                      // reuse n1 (window-ordered)
    unsigned short* attn_feat = (unsigned short*)(ws + 47185920);           // reuse qkv head (token order)
    unsigned short* x_mid     = (unsigned short*)(ws + 94371840);           // reuse qkv mid
    unsigned short* n2        = (unsigned short*)(ws + 141557760);          // reuse qkv tail
    unsigned short* h         = (unsigned short*)(ws);                      // [0, 94.4MB)
    unsigned short* h_s       = (unsigned short*)(ws + 141557760);          // [141.6, 235.9MB)
    float*          pooled    = (float*)(ws + 235929600);                   // 1440 B
    float*          cmv       = (float*)(ws + 235931040);                   // 1440 B
    unsigned short* wbf       = (unsigned short*)(ws + 235932480);          // 518,400 B
    float*          wT1       = (float*)(ws + 236450880);                   // 25,920 B
    float*          wT2       = (float*)(ws + 236476800);                   // 51,840 B
    unsigned short* br3       = (unsigned short*)(ws + 236528640);          // 49,152 B
    unsigned short* wqkv_b  = wbf;
    unsigned short* wproj_b = wbf + 97200;
    unsigned short* wffn1_b = wbf + 129600;
    unsigned short* wffn2_b = wbf + 194400;
    float* out = (float*)d_out;

    hipMemsetAsync(pooled, 0, 2880, stream);

    // 0. weight prep (incl. fragment-ordered bf16 b_rel)
    convw_kernel<<<1185, 256, 0, stream>>>(w_qkv, w_proj, ffn_w1, ffn_w2,
                                           conv_dw, ffn_dw, b_rel, wbf, wT1, wT2, br3);
    // 1. LN1: x(fp32) -> n1(bf16)
    ln_kernel<float><<<BL / 4, 256, 0, stream>>>(x, n1_g, n1_b, n1);
    // 2. qkvw = n1 @ w_qkv^T, rows stored window-ordered (PERM=1); grid (n,m)
    gemm_kernel<0, false, false, 1, unsigned short><<<dim3(9, BL / 256), 256, 0, stream>>>(
        n1, CH, wqkv_b, nullptr, nullptr, 0, qkvw, 540, 540, CH);
    // 3. conv branch: gelu(dwconv3x3(n1)) -> conv_feat
    dwconv_kernel<CH, true><<<1472, 256, 0, stream>>>(n1, wT1, conv_feat);
    // 4. pooled = sum_L conv_feat
    pool_kernel<<<BATCH * 128, 64, 0, stream>>>(conv_feat, pooled);
    // 5. cm
    cm_kernel<<<1, 256, 0, stream>>>(pooled, cg_w1, cg_w2, cmv);
    // 6. window attention (MFMA): one wave per (window, head)
    attn_kernel<<<2048 * 6, 64, 0, stream>>>(qkvw, br3, attn_out);
    // 7. attn_feat = attn_out @ w_proj^T + b_proj; X window-ordered, Y token order (PERM=2)
    gemm_kernel<0, true, false, 2, unsigned short><<<dim3(3, BL / 256), 256, 0, stream>>>(
        attn_out, CH, wproj_b, b_proj, nullptr, 0, attn_feat, CH, CH, CH);
    // 8. x_mid = x + attn_feat*cm + conv_feat  (bf16)
    resid_kernel<<<(BL * CH / 4) / 256, 256, 0, stream>>>(x, attn_feat, conv_feat, cmv, x_mid);
    // 9. LN2
    ln_kernel<unsigned short><<<BL / 4, 256, 0, stream>>>(x_mid, n2_g, n2_b, n2);
    // 10. h = gelu(n2 @ ffn_w1^T)
    gemm_kernel<1, false, false, 0, unsigned short><<<dim3(6, BL / 256), 256, 0, stream>>>(
        n2, CH, wffn1_b, nullptr, nullptr, 0, h, HDF, HDF, CH);
    // 11. h_s = dwconv3x3(h)
    dwconv_kernel<HDF, false><<<2880, 256, 0, stream>>>(h, wT2, h_s);
    // 12. out(fp32) = x_mid + h_s @ ffn_w2^T
    gemm_kernel<0, false, true, 0, float><<<dim3(3, BL / 256), 256, 0, stream>>>(
        h_s, HDF, wffn2_b, nullptr, x_mid, CH, out, CH, CH, HDF);
}

// Round 4
// 1002.134 us; speedup vs baseline: 1.0496x; 1.0496x over previous
//
#include <hip/hip_runtime.h>
#include <hip/hip_bf16.h>
#include <math.h>

// ---------------- constants (problem is fixed-shape) ----------------
// B=2, H=W=256, L=65536, C=180, NH=6, hd=30, WS=8, hd_ffn=360
// I/O dtype: fp32 (per reference). Internals: bf16 (MFMA), fp32 accum.
#define BATCH 2
#define IMG 256
#define LTOK 65536
#define CH 180
#define BL (BATCH * LTOK)            // 131072 tokens
#define HDF 360

using frag_ab = __attribute__((ext_vector_type(8))) short;   // 8 bf16 in 4 VGPRs
using frag_cd = __attribute__((ext_vector_type(4))) float;   // 4 f32 acc

__device__ __forceinline__ float b2f(unsigned short u) {
    union { unsigned int i; float f; } v; v.i = ((unsigned int)u) << 16; return v.f;
}
__device__ __forceinline__ float blo(unsigned int u) {
    union { unsigned int i; float f; } v; v.i = u << 16; return v.f;
}
__device__ __forceinline__ float bhi(unsigned int u) {
    union { unsigned int i; float f; } v; v.i = u & 0xffff0000u; return v.f;
}
__device__ __forceinline__ unsigned short f2b(float f) {
    union { float f; unsigned int i; } v; v.f = f;
    unsigned int x = v.i;
    unsigned int r = (x + 0x7fffu + ((x >> 16) & 1u)) >> 16;   // RNE
    return (unsigned short)r;
}
__device__ __forceinline__ float gelu_f(float x) {
    return 0.5f * x * (1.0f + erff(x * 0.70710678118654752f));
}

// row-index permutations for window attention, folded into GEMM epilogues.
// PERM=1: token-order row -> window-order position. PERM=2: inverse.
template <int PERM>
__device__ __forceinline__ int perm_row(int row) {
    if (PERM == 1) {
        int b = row >> 16, l = row & 65535;
        int y = l >> 8, x = l & 255;
        return (b << 16) + ((((y >> 3) << 5) + (x >> 3)) << 6) + ((y & 7) << 3) + (x & 7);
    } else if (PERM == 2) {
        int b = row >> 16, wv = row & 65535;
        int wid = wv >> 6, t = wv & 63;
        int wy = wid >> 5, wx = wid & 31;
        return (b << 16) + ((((wy << 3) + (t >> 3))) << 8) + (wx << 3) + (t & 7);
    }
    return row;
}

// ---------------- one-shot weight prep ----------------
// wbf: bf16 copies of the 4 GEMM weights. wT1/wT2: tap-major dwconv weights.
// br3: b_rel re-ordered to MFMA fragment order per (head, lane):
//      br3[h*4096 + lane*64 + (mt*16+nt*4+r)] = bf16(b_rel[h][mt*16+(lane>>4)*4+r][nt*16+(lane&15)])
__global__ __launch_bounds__(256) void convw_kernel(
    const float* __restrict__ a, const float* __restrict__ b,
    const float* __restrict__ c, const float* __restrict__ d,
    const float* __restrict__ cdw, const float* __restrict__ fdw,
    const float* __restrict__ brel,
    unsigned short* __restrict__ wbf, float* __restrict__ wT1, float* __restrict__ wT2,
    unsigned short* __restrict__ br3)
{
    int g = blockIdx.x * 256 + threadIdx.x;
    if (g < 259200) {
        float v;
        if      (g < 97200)  v = a[g];
        else if (g < 129600) v = b[g - 97200];
        else if (g < 194400) v = c[g - 129600];
        else                 v = d[g - 194400];
        wbf[g] = f2b(v);
    } else if (g < 265680) {
        int i = g - 259200;               // tap-major [9][180]
        int tap = i / 180, ch = i % 180;
        wT1[i] = cdw[ch * 9 + tap];
    } else if (g < 278640) {
        int i = g - 265680;               // [9][360]
        int tap = i / 360, ch = i % 360;
        wT2[i] = fdw[ch * 9 + tap];
    } else if (g < 303216) {
        int i = g - 278640;               // 6*4096 fragment-ordered bias
        int h = i >> 12;
        int rem = i & 4095;
        int lane = rem >> 6;
        int j = rem & 63;
        int mt = j >> 4, nt = (j >> 2) & 3, r = j & 3;
        int row = mt * 16 + (lane >> 4) * 4 + r;
        int col = nt * 16 + (lane & 15);
        br3[i] = f2b(brel[h * 4096 + row * 64 + col]);
    }
}

// ---------------- LayerNorm: one wave per token, vectorized (45 active lanes) ----------------
__device__ __forceinline__ void ld4(const float* p, float v[4]) {
    float4 t = *(const float4*)p; v[0]=t.x; v[1]=t.y; v[2]=t.z; v[3]=t.w;
}
__device__ __forceinline__ void ld4(const unsigned short* p, float v[4]) {
    ushort4 t = *(const ushort4*)p; v[0]=b2f(t.x); v[1]=b2f(t.y); v[2]=b2f(t.z); v[3]=b2f(t.w);
}

template <typename TIN>
__global__ __launch_bounds__(256) void ln_kernel(
    const TIN* __restrict__ x, const float* __restrict__ g,
    const float* __restrict__ bta, unsigned short* __restrict__ out)
{
    int wave = threadIdx.x >> 6, lane = threadIdx.x & 63;
    int tok = blockIdx.x * 4 + wave;
    const bool act = lane < 45;                 // 45*4 = 180 channels
    float v[4] = {0.f, 0.f, 0.f, 0.f};
    const TIN* row = x + (size_t)tok * CH;
    if (act) ld4(row + lane * 4, v);
    float s  = v[0] + v[1] + v[2] + v[3];
    float sq = v[0]*v[0] + v[1]*v[1] + v[2]*v[2] + v[3]*v[3];
    #pragma unroll
    for (int off = 32; off > 0; off >>= 1) {
        s  += __shfl_xor(s, off);
        sq += __shfl_xor(sq, off);
    }
    float mean = s * (1.f / CH);
    float var  = sq * (1.f / CH) - mean * mean;
    float rstd = rsqrtf(var + 1e-5f);
    if (act) {
        float4 gg = *(const float4*)&g[lane * 4];
        float4 bb = *(const float4*)&bta[lane * 4];
        unsigned int o0 = (unsigned int)f2b((v[0]-mean)*rstd*gg.x + bb.x)
                        | ((unsigned int)f2b((v[1]-mean)*rstd*gg.y + bb.y) << 16);
        unsigned int o1 = (unsigned int)f2b((v[2]-mean)*rstd*gg.z + bb.z)
                        | ((unsigned int)f2b((v[3]-mean)*rstd*gg.w + bb.w) << 16);
        *(uint2*)(out + (size_t)tok * CH + lane * 4) = make_uint2(o0, o1);
    }
}

// ---------------- generic MFMA GEMM, no-LDS panel-ownership form ----------------
// One block owns a 128-row A panel (wave w: rows w*32..w*32+31) and loops over ALL
// n-tiles internally. A is fetched from HBM exactly once chip-wide (no inter-block
// sharing); B (tiny) is L1/L2-resident. Fragments load directly from global --
// no LDS, no barriers. K-tail: BOTH operands' out-of-range elements zeroed
// (NaN-proofing: garbage*0 in MFMA would still poison the row).
__device__ __forceinline__ void stv(float* p, float v) { *p = v; }
__device__ __forceinline__ void stv(unsigned short* p, float v) { *p = f2b(v); }

__device__ __forceinline__ frag_ab ldg_frag(const unsigned short* p) {
    union { frag_ab f; uint2 u[2]; } t;
    t.u[0] = *(const uint2*)p;
    t.u[1] = *(const uint2*)(p + 4);
    return t.f;
}
__device__ __forceinline__ frag_ab ldg_frag_tail(const unsigned short* p, int kcol0, int K) {
    union { frag_ab f; unsigned short s[8]; } t;
    #pragma unroll
    for (int j = 0; j < 8; ++j)
        t.s[j] = (kcol0 + j < K) ? p[j] : (unsigned short)0;
    return t.f;
}

template <int ACT, bool HAS_BIAS, bool HAS_RES, int PERM, typename TOUT>
__global__ __launch_bounds__(256) void gemm_kernel(
    const unsigned short* __restrict__ X, int ldx,
    const unsigned short* __restrict__ Wt,
    const float* __restrict__ bias,
    const unsigned short* __restrict__ res, int ldr,
    TOUT* __restrict__ Y, int ldy,
    int N, int K)
{
    const int tid = threadIdx.x;
    const int wave = tid >> 6;
    const int lane = tid & 63;
    const int l16 = lane & 15;
    const int q = lane >> 4;
    const int m0 = blockIdx.x * 128;

    // A fragment base pointers: row m0 + wave*32 + mb*16 + l16, k-offset q*8
    const unsigned short* aptr0 = X + (size_t)(m0 + wave * 32 + l16) * ldx + q * 8;
    const unsigned short* aptr1 = aptr0 + (size_t)16 * ldx;

    const int KF = K & ~31;            // full 32-wide K steps
    const int ktail0 = KF + q * 8;     // first k-col of this lane's tail frag

    for (int n0 = 0; n0 < N; n0 += 64) {
        frag_cd acc[2][4];
        #pragma unroll
        for (int mb = 0; mb < 2; ++mb)
            #pragma unroll
            for (int nb = 0; nb < 4; ++nb)
                acc[mb][nb] = (frag_cd){0.f, 0.f, 0.f, 0.f};

        const unsigned short* bptr[4];
        #pragma unroll
        for (int nb = 0; nb < 4; ++nb)
            bptr[nb] = Wt + (size_t)(n0 + nb * 16 + l16) * K + q * 8;

        for (int k0 = 0; k0 < KF; k0 += 32) {
            frag_ab a0 = ldg_frag(aptr0 + k0);
            frag_ab a1 = ldg_frag(aptr1 + k0);
            #pragma unroll
            for (int nb = 0; nb < 4; ++nb) {
                frag_ab b = ldg_frag(bptr[nb] + k0);
                acc[0][nb] = __builtin_amdgcn_mfma_f32_16x16x32_bf16(a0, b, acc[0][nb], 0, 0, 0);
                acc[1][nb] = __builtin_amdgcn_mfma_f32_16x16x32_bf16(a1, b, acc[1][nb], 0, 0, 0);
            }
        }
        if (KF < K) {
            frag_ab a0 = ldg_frag_tail(aptr0 + KF, ktail0, K);
            frag_ab a1 = ldg_frag_tail(aptr1 + KF, ktail0, K);
            #pragma unroll
            for (int nb = 0; nb < 4; ++nb) {
                frag_ab b = ldg_frag_tail(bptr[nb] + KF, ktail0, K);
                acc[0][nb] = __builtin_amdgcn_mfma_f32_16x16x32_bf16(a0, b, acc[0][nb], 0, 0, 0);
                acc[1][nb] = __builtin_amdgcn_mfma_f32_16x16x32_bf16(a1, b, acc[1][nb], 0, 0, 0);
            }
        }

        // ---- epilogue for this n-tile ----
        #pragma unroll
        for (int nb = 0; nb < 4; ++nb) {
            const int col = n0 + nb * 16 + l16;
            if (col < N) {
                float bv = 0.f;
                if (HAS_BIAS) bv = bias[col];
                #pragma unroll
                for (int mb = 0; mb < 2; ++mb) {
                    #pragma unroll
                    for (int r = 0; r < 4; ++r) {
                        int row = m0 + wave * 32 + mb * 16 + q * 4 + r;
                        int orow = perm_row<PERM>(row);
                        float v = acc[mb][nb][r] + bv;
                        if (ACT == 1) v = gelu_f(v);
                        if (HAS_RES) v += b2f(res[(size_t)orow * ldr + col]);
                        stv(&Y[(size_t)orow * ldy + col], v);
                    }
                }
            }
        }
    }
}

// ---------------- window attention: MFMA, one wave per (window, head) ----------------
// qkvw is WINDOW-ORDERED: row w64 = w*64 + t, cols [q:h*30+d][k:180+...][v:360+...]
// S = Q@K^T via mfma_f32_16x16x32_bf16 (A=[m][k] row-chunk pattern, B=[n][k]);
// C/D layout: col=lane&15, row=(lane>>4)*4+reg  (same convention as gemm_kernel).
// Softmax: per-row max/sum via in-register nt-reduce + shfl_xor(1,2,4,8) over the
// 16-lane column group. P (unnormalized bf16) -> LDS; V staged transposed into LDS
// so the PV B-operand is a linear ds_read_b128. 1/sum folded into the O epilogue.
__global__ __launch_bounds__(64) void attn_kernel(
    const unsigned short* __restrict__ qkvw,
    const unsigned short* __restrict__ br3,
    unsigned short* __restrict__ attn_out)
{
    __shared__ unsigned short Pl[64][72];   // P bf16, stride 72 (144 B: 16B-aligned rows)
    __shared__ unsigned short VT[32][72];   // V^T bf16 [d][key], rows 30,31 zeroed
    const int blk = blockIdx.x;             // 0..12287
    const int h = blk % 6;
    const int w = blk / 6;
    const int lane = threadIdx.x;
    const int l16 = lane & 15;
    const int g4 = lane >> 4;
    const float scale = 0.18257418583505536f;  // 30^-0.5

    const unsigned short* base = qkvw + (size_t)w * (64 * 540) + h * 30;

    // ---- Q (A) and K (B) fragments straight from global (4B-aligned uint2 loads) ----
    frag_ab qf[4], kf[4];
    #pragma unroll
    for (int t = 0; t < 4; ++t) {
        const unsigned short* pq = base + (size_t)(t * 16 + l16) * 540 + g4 * 8;
        union { frag_ab f; uint2 u[2]; } tq, tk;
        tq.u[0] = *(const uint2*)pq;        tq.u[1] = *(const uint2*)(pq + 4);
        tk.u[0] = *(const uint2*)(pq + 180); tk.u[1] = *(const uint2*)(pq + 184);
        if (g4 == 3) { tk.f[6] = 0; tk.f[7] = 0; }   // zero K pad cols d=30,31
        qf[t] = tq.f; kf[t] = tk.f;
    }

    // ---- fragment-ordered bias (bf16, coalesced uint4 loads) ----
    unsigned int brw[32];
    {
        const unsigned short* bp = br3 + ((size_t)h << 12) + lane * 64;
        #pragma unroll
        for (int c2 = 0; c2 < 8; ++c2)
            *(uint4*)&brw[c2 * 4] = *(const uint4*)(bp + c2 * 8);
    }

    // ---- S = Q @ K^T : 16 MFMA ----
    frag_cd s[4][4];
    #pragma unroll
    for (int mt = 0; mt < 4; ++mt)
        #pragma unroll
        for (int nt = 0; nt < 4; ++nt)
            s[mt][nt] = (frag_cd){0.f, 0.f, 0.f, 0.f};
    #pragma unroll
    for (int mt = 0; mt < 4; ++mt)
        #pragma unroll
        for (int nt = 0; nt < 4; ++nt)
            s[mt][nt] = __builtin_amdgcn_mfma_f32_16x16x32_bf16(qf[mt], kf[nt], s[mt][nt], 0, 0, 0);

    // ---- stage V^T into LDS (overlaps with MFMA latency) ----
    {
        const unsigned short* pv = base + (size_t)lane * 540 + 360;
        #pragma unroll
        for (int d2 = 0; d2 < 15; ++d2) {
            unsigned int u = *(const unsigned int*)(pv + 2 * d2);
            VT[2 * d2][lane]     = (unsigned short)(u & 0xffffu);
            VT[2 * d2 + 1][lane] = (unsigned short)(u >> 16);
        }
        VT[30][lane] = 0; VT[31][lane] = 0;
    }

    // ---- bias + row softmax (unnormalized P -> LDS), inv kept per (mt,reg) ----
    float inv[4][4];
    #pragma unroll
    for (int mt = 0; mt < 4; ++mt) {
        #pragma unroll
        for (int r = 0; r < 4; ++r) {
            float a0 = s[mt][0][r] * scale + (((0 * 4 + r) & 1) ? bhi(brw[(mt * 16 + 0 + r) >> 1]) : blo(brw[(mt * 16 + 0 + r) >> 1]));
            float a1 = s[mt][1][r] * scale + (((1 * 4 + r) & 1) ? bhi(brw[(mt * 16 + 4 + r) >> 1]) : blo(brw[(mt * 16 + 4 + r) >> 1]));
            float a2 = s[mt][2][r] * scale + (((2 * 4 + r) & 1) ? bhi(brw[(mt * 16 + 8 + r) >> 1]) : blo(brw[(mt * 16 + 8 + r) >> 1]));
            float a3 = s[mt][3][r] * scale + (((3 * 4 + r) & 1) ? bhi(brw[(mt * 16 + 12 + r) >> 1]) : blo(brw[(mt * 16 + 12 + r) >> 1]));
            float m = fmaxf(fmaxf(a0, a1), fmaxf(a2, a3));
            m = fmaxf(m, __shfl_xor(m, 1));
            m = fmaxf(m, __shfl_xor(m, 2));
            m = fmaxf(m, __shfl_xor(m, 4));
            m = fmaxf(m, __shfl_xor(m, 8));
            float e0 = __expf(a0 - m), e1 = __expf(a1 - m);
            float e2 = __expf(a2 - m), e3 = __expf(a3 - m);
            float sum = e0 + e1 + e2 + e3;
            sum += __shfl_xor(sum, 1);
            sum += __shfl_xor(sum, 2);
            sum += __shfl_xor(sum, 4);
            sum += __shfl_xor(sum, 8);
            inv[mt][r] = 1.f / sum;
            int row = mt * 16 + g4 * 4 + r;
            Pl[row][l16]      = f2b(e0);
            Pl[row][16 + l16] = f2b(e1);
            Pl[row][32 + l16] = f2b(e2);
            Pl[row][48 + l16] = f2b(e3);
        }
    }
    __syncthreads();

    // ---- O = P @ V : A-frags from Pl, B-frags from VT, 16 MFMA ----
    frag_ab pf[4][2];
    #pragma unroll
    for (int mt = 0; mt < 4; ++mt)
        #pragma unroll
        for (int kt = 0; kt < 2; ++kt)
            pf[mt][kt] = *(const frag_ab*)&Pl[mt * 16 + l16][kt * 32 + g4 * 8];
    frag_ab vf[2][2];
    #pragma unroll
    for (int nt = 0; nt < 2; ++nt)
        #pragma unroll
        for (int kt = 0; kt < 2; ++kt)
            vf[nt][kt] = *(const frag_ab*)&VT[nt * 16 + l16][kt * 32 + g4 * 8];

    frag_cd o[4][2];
    #pragma unroll
    for (int mt = 0; mt < 4; ++mt)
        #pragma unroll
        for (int nt = 0; nt < 2; ++nt)
            o[mt][nt] = (frag_cd){0.f, 0.f, 0.f, 0.f};
    #pragma unroll
    for (int mt = 0; mt < 4; ++mt)
        #pragma unroll
        for (int nt = 0; nt < 2; ++nt)
            #pragma unroll
            for (int kt = 0; kt < 2; ++kt)
                o[mt][nt] = __builtin_amdgcn_mfma_f32_16x16x32_bf16(pf[mt][kt], vf[nt][kt], o[mt][nt], 0, 0, 0);

    // ---- epilogue: normalize rows by inv, store bf16 (cols 30,31 dropped) ----
    unsigned short* ob = attn_out + (size_t)w * (64 * CH) + h * 30;
    #pragma unroll
    for (int mt = 0; mt < 4; ++mt) {
        #pragma unroll
        for (int r = 0; r < 4; ++r) {
            int row = mt * 16 + g4 * 4 + r;
            float iv = inv[mt][r];
            unsigned short* op = ob + (size_t)row * CH;
            op[l16] = f2b(o[mt][0][r] * iv);
            if (l16 < 14) op[16 + l16] = f2b(o[mt][1][r] * iv);
        }
    }
}

// ---------------- depthwise 3x3 SAME conv, vectorized column-walk ----------------
template <int C, bool DO_GELU>
__global__ __launch_bounds__(256) void dwconv_kernel(
    const unsigned short* __restrict__ in, const float* __restrict__ wT,
    unsigned short* __restrict__ out)
{
    constexpr int NG = (C + 7) / 8;
    constexpr int TY = 8;
    int gid = blockIdx.x * 256 + threadIdx.x;
    int cg = gid % NG;
    int t  = gid / NG;
    int x  = t % IMG;
    int t2 = t / IMG;
    int yb = t2 & 31;
    int bi = t2 >> 5;
    if (bi >= BATCH) return;
    const int c0 = cg * 8;
    const int y0 = yb * TY;

    float w9[9][8];
    #pragma unroll
    for (int tp = 0; tp < 9; ++tp) {
        float4 wa = *(const float4*)&wT[tp * C + c0];
        float4 wb = *(const float4*)&wT[tp * C + c0 + 4];
        w9[tp][0]=wa.x; w9[tp][1]=wa.y; w9[tp][2]=wa.z; w9[tp][3]=wa.w;
        w9[tp][4]=wb.x; w9[tp][5]=wb.y; w9[tp][6]=wb.z; w9[tp][7]=wb.w;
    }

    unsigned int rr[3][3][4];

    auto load_row = [&](int y, unsigned int dst[3][4]) {
        if ((unsigned)y >= (unsigned)IMG) {
            #pragma unroll
            for (int cc = 0; cc < 3; ++cc)
                #pragma unroll
                for (int k = 0; k < 4; ++k) dst[cc][k] = 0u;
            return;
        }
        size_t base = ((size_t)((bi << 16) + (y << 8) + x)) * C + c0;
        #pragma unroll
        for (int cc = 0; cc < 3; ++cc) {
            int xx = x + cc - 1;
            if ((unsigned)xx >= (unsigned)IMG) {
                dst[cc][0] = dst[cc][1] = dst[cc][2] = dst[cc][3] = 0u;
                continue;
            }
            const unsigned short* p = in + base + (ptrdiff_t)(cc - 1) * C;
            uint2 u0 = *(const uint2*)p;
            uint2 u1 = *(const uint2*)(p + 4);
            dst[cc][0] = u0.x; dst[cc][1] = u0.y; dst[cc][2] = u1.x; dst[cc][3] = u1.y;
        }
    };

    load_row(y0 - 1, rr[0]);
    load_row(y0,     rr[1]);

    #pragma unroll
    for (int dy = 0; dy < TY; ++dy) {
        load_row(y0 + dy + 1, rr[(dy + 2) % 3]);
        float acc[8];
        #pragma unroll
        for (int j = 0; j < 8; ++j) acc[j] = 0.f;
        #pragma unroll
        for (int ky = 0; ky < 3; ++ky) {
            unsigned int (*row)[4] = rr[(dy + ky) % 3];
            #pragma unroll
            for (int kx = 0; kx < 3; ++kx) {
                const float* wp = w9[ky * 3 + kx];
                const unsigned int* u = row[kx];
                acc[0] += blo(u[0]) * wp[0];
                acc[1] += bhi(u[0]) * wp[1];
                acc[2] += blo(u[1]) * wp[2];
                acc[3] += bhi(u[1]) * wp[3];
                acc[4] += blo(u[2]) * wp[4];
                acc[5] += bhi(u[2]) * wp[5];
                acc[6] += blo(u[3]) * wp[6];
                acc[7] += bhi(u[3]) * wp[7];
            }
        }
        if (DO_GELU) {
            #pragma unroll
            for (int j = 0; j < 8; ++j) acc[j] = gelu_f(acc[j]);
        }
        size_t ob = ((size_t)((bi << 16) + ((y0 + dy) << 8) + x)) * C + c0;
        unsigned int o0 = (unsigned int)f2b(acc[0]) | ((unsigned int)f2b(acc[1]) << 16);
        unsigned int o1 = (unsigned int)f2b(acc[2]) | ((unsigned int)f2b(acc[3]) << 16);
        *(uint2*)(out + ob) = make_uint2(o0, o1);
        if (c0 + 8 <= C) {
            unsigned int o2 = (unsigned int)f2b(acc[4]) | ((unsigned int)f2b(acc[5]) << 16);
            unsigned int o3 = (unsigned int)f2b(acc[6]) | ((unsigned int)f2b(acc[7]) << 16);
            *(uint2*)(out + ob + 4) = make_uint2(o2, o3);
        }
    }
}

// ---------------- sum-pool over L per (b,c), ushort4 ----------------
__global__ __launch_bounds__(64) void pool_kernel(
    const unsigned short* __restrict__ cf, float* __restrict__ pooled)
{
    int t = threadIdx.x;
    if (t >= 45) return;
    int b = blockIdx.x >> 7;
    int chunk = blockIdx.x & 127;
    const unsigned short* base = cf + (size_t)(b * LTOK + chunk * 512) * CH + t * 4;
    float s0 = 0.f, s1 = 0.f, s2 = 0.f, s3 = 0.f;
    for (int i = 0; i < 512; ++i) {
        ushort4 v = *(const ushort4*)(base + (size_t)i * CH);
        s0 += b2f(v.x); s1 += b2f(v.y); s2 += b2f(v.z); s3 += b2f(v.w);
    }
    atomicAdd(&pooled[b * CH + t * 4 + 0], s0);
    atomicAdd(&pooled[b * CH + t * 4 + 1], s1);
    atomicAdd(&pooled[b * CH + t * 4 + 2], s2);
    atomicAdd(&pooled[b * CH + t * 4 + 3], s3);
}

// ---------------- channel gate ----------------
__global__ __launch_bounds__(256) void cm_kernel(
    const float* __restrict__ pooled, const float* __restrict__ w1,
    const float* __restrict__ w2, float* __restrict__ cm)
{
    __shared__ float p[BATCH][CH];
    __shared__ float g1[BATCH][22];
    int t = threadIdx.x;
    for (int idx = t; idx < BATCH * CH; idx += 256)
        p[idx / CH][idx % CH] = pooled[idx] * (1.f / (float)LTOK);
    __syncthreads();
    if (t < BATCH * 22) {
        int b = t / 22, u = t % 22;
        float s = 0.f;
        for (int c = 0; c < CH; ++c) s += p[b][c] * w1[u * CH + c];
        g1[b][u] = gelu_f(s);
    }
    __syncthreads();
    for (int idx = t; idx < BATCH * CH; idx += 256) {
        int b = idx / CH, c = idx % CH;
        float s = 0.f;
        for (int u = 0; u < 22; ++u) s += g1[b][u] * w2[c * 22 + u];
        cm[idx] = 1.f / (1.f + __expf(-s));
    }
}

// ---------------- residual 1, 4 channels/thread ----------------
__global__ __launch_bounds__(256) void resid_kernel(
    const float* __restrict__ x, const unsigned short* __restrict__ attn_feat,
    const unsigned short* __restrict__ conv_feat, const float* __restrict__ cm,
    unsigned short* __restrict__ x_mid)
{
    int gid = blockIdx.x * 256 + threadIdx.x;     // BL*CH/4 threads
    int c4 = gid % 45;
    int b = gid / (LTOK * 45);
    float4 xv = ((const float4*)x)[gid];
    ushort4 a = ((const ushort4*)attn_feat)[gid];
    ushort4 c = ((const ushort4*)conv_feat)[gid];
    float4 m = *(const float4*)&cm[b * CH + c4 * 4];
    unsigned int o0 = (unsigned int)f2b(xv.x + b2f(a.x) * m.x + b2f(c.x))
                    | ((unsigned int)f2b(xv.y + b2f(a.y) * m.y + b2f(c.y)) << 16);
    unsigned int o1 = (unsigned int)f2b(xv.z + b2f(a.z) * m.z + b2f(c.z))
                    | ((unsigned int)f2b(xv.w + b2f(a.w) * m.w + b2f(c.w)) << 16);
    ((uint2*)x_mid)[gid] = make_uint2(o0, o1);
}

// ---------------- launch ----------------
extern "C" void kernel_launch(void* const* d_in, const int* in_sizes, int n_in,
                              void* d_out, int out_size, void* d_ws, size_t ws_size,
                              hipStream_t stream)
{
    const float* x       = (const float*)d_in[0];
    const float* w_qkv   = (const float*)d_in[1];
    const float* b_rel   = (const float*)d_in[2];
    const float* w_proj  = (const float*)d_in[3];
    const float* b_proj  = (const float*)d_in[4];
    const float* conv_dw = (const float*)d_in[5];
    const float* cg_w1   = (const float*)d_in[6];
    const float* cg_w2   = (const float*)d_in[7];
    const float* ffn_w1  = (const float*)d_in[8];
    const float* ffn_dw  = (const float*)d_in[9];
    const float* ffn_w2  = (const float*)d_in[10];
    const float* n1_g    = (const float*)d_in[11];
    const float* n1_b    = (const float*)d_in[12];
    const float* n2_g    = (const float*)d_in[13];
    const float* n2_b    = (const float*)d_in[14];

    // ---- workspace layout (bytes), peak ~225.7 MiB ----
    char* ws = (char*)d_ws;
    unsigned short* n1        = (unsigned short*)(ws);                      // [0, 47.2MB)
    unsigned short* qkvw      = (unsigned short*)(ws + 47185920);           // [47.2, 188.7MB) window-ordered
    unsigned short* conv_feat = (unsigned short*)(ws + 188743680);          // [188.7, 235.9MB)
    unsigned short* attn_out  = (unsigned short*)(ws);                      // reuse n1 (window-ordered)
    unsigned short* attn_feat = (unsigned short*)(ws + 47185920);           // reuse qkv head (token order)
    unsigned short* x_mid     = (unsigned short*)(ws + 94371840);           // reuse qkv mid
    unsigned short* n2        = (unsigned short*)(ws + 141557760);          // reuse qkv tail
    unsigned short* h         = (unsigned short*)(ws);                      // [0, 94.4MB)
    unsigned short* h_s       = (unsigned short*)(ws + 141557760);          // [141.6, 235.9MB)
    float*          pooled    = (float*)(ws + 235929600);                   // 1440 B
    float*          cmv       = (float*)(ws + 235931040);                   // 1440 B
    unsigned short* wbf       = (unsigned short*)(ws + 235932480);          // 518,400 B
    float*          wT1       = (float*)(ws + 236450880);                   // 25,920 B
    float*          wT2       = (float*)(ws + 236476800);                   // 51,840 B
    unsigned short* br3       = (unsigned short*)(ws + 236528640);          // 49,152 B
    unsigned short* wqkv_b  = wbf;
    unsigned short* wproj_b = wbf + 97200;
    unsigned short* wffn1_b = wbf + 129600;
    unsigned short* wffn2_b = wbf + 194400;
    float* out = (float*)d_out;

    hipMemsetAsync(pooled, 0, 2880, stream);

    // 0. weight prep (incl. fragment-ordered bf16 b_rel)
    convw_kernel<<<1185, 256, 0, stream>>>(w_qkv, w_proj, ffn_w1, ffn_w2,
                                           conv_dw, ffn_dw, b_rel, wbf, wT1, wT2, br3);
    // 1. LN1: x(fp32) -> n1(bf16)
    ln_kernel<float><<<BL / 4, 256, 0, stream>>>(x, n1_g, n1_b, n1);
    // 2. qkvw = n1 @ w_qkv^T, rows stored window-ordered (PERM=1)
    gemm_kernel<0, false, false, 1, unsigned short><<<BL / 128, 256, 0, stream>>>(
        n1, CH, wqkv_b, nullptr, nullptr, 0, qkvw, 540, 540, CH);
    // 3. conv branch: gelu(dwconv3x3(n1)) -> conv_feat
    dwconv_kernel<CH, true><<<1472, 256, 0, stream>>>(n1, wT1, conv_feat);
    // 4. pooled = sum_L conv_feat
    pool_kernel<<<BATCH * 128, 64, 0, stream>>>(conv_feat, pooled);
    // 5. cm
    cm_kernel<<<1, 256, 0, stream>>>(pooled, cg_w1, cg_w2, cmv);
    // 6. window attention (MFMA): one wave per (window, head)
    attn_kernel<<<2048 * 6, 64, 0, stream>>>(qkvw, br3, attn_out);
    // 7. attn_feat = attn_out @ w_proj^T + b_proj; X window-ordered, Y token order (PERM=2)
    gemm_kernel<0, true, false, 2, unsigned short><<<BL / 128, 256, 0, stream>>>(
        attn_out, CH, wproj_b, b_proj, nullptr, 0, attn_feat, CH, CH, CH);
    // 8. x_mid = x + attn_feat*cm + conv_feat  (bf16)
    resid_kernel<<<(BL * CH / 4) / 256, 256, 0, stream>>>(x, attn_feat, conv_feat, cmv, x_mid);
    // 9. LN2
    ln_kernel<unsigned short><<<BL / 4, 256, 0, stream>>>(x_mid, n2_g, n2_b, n2);
    // 10. h = gelu(n2 @ ffn_w1^T)
    gemm_kernel<1, false, false, 0, unsigned short><<<BL / 128, 256, 0, stream>>>(
        n2, CH, wffn1_b, nullptr, nullptr, 0, h, HDF, HDF, CH);
    // 11. h_s = dwconv3x3(h)
    dwconv_kernel<HDF, false><<<2880, 256, 0, stream>>>(h, wT2, h_s);
    // 12. out(fp32) = x_mid + h_s @ ffn_w2^T
    gemm_kernel<0, false, true, 0, float><<<BL / 128, 256, 0, stream>>>(
        h_s, HDF, wffn2_b, nullptr, x_mid, CH, out, CH, CH, HDF);
}

// Round 5
// 951.152 us; speedup vs baseline: 1.1058x; 1.0536x over previous
//
#include <hip/hip_runtime.h>
#include <hip/hip_bf16.h>
#include <math.h>

// ---------------- constants (problem is fixed-shape) ----------------
// B=2, H=W=256, L=65536, C=180, NH=6, hd=30, WS=8, hd_ffn=360
// I/O dtype: fp32 (per reference). Internals: bf16 (MFMA), fp32 accum.
#define BATCH 2
#define IMG 256
#define LTOK 65536
#define CH 180
#define BL (BATCH * LTOK)            // 131072 tokens
#define HDF 360

using frag_ab = __attribute__((ext_vector_type(8))) short;   // 8 bf16 in 4 VGPRs
using frag_cd = __attribute__((ext_vector_type(4))) float;   // 4 f32 acc

__device__ __forceinline__ float b2f(unsigned short u) {
    union { unsigned int i; float f; } v; v.i = ((unsigned int)u) << 16; return v.f;
}
__device__ __forceinline__ float blo(unsigned int u) {
    union { unsigned int i; float f; } v; v.i = u << 16; return v.f;
}
__device__ __forceinline__ float bhi(unsigned int u) {
    union { unsigned int i; float f; } v; v.i = u & 0xffff0000u; return v.f;
}
__device__ __forceinline__ unsigned short f2b(float f) {
    union { float f; unsigned int i; } v; v.f = f;
    unsigned int x = v.i;
    unsigned int r = (x + 0x7fffu + ((x >> 16) & 1u)) >> 16;   // RNE
    return (unsigned short)r;
}
__device__ __forceinline__ float gelu_f(float x) {
    return 0.5f * x * (1.0f + erff(x * 0.70710678118654752f));
}

// row-index permutations for window attention, folded into GEMM epilogues.
// PERM=1: token-order row -> window-order position. PERM=2: inverse.
template <int PERM>
__device__ __forceinline__ int perm_row(int row) {
    if (PERM == 1) {
        int b = row >> 16, l = row & 65535;
        int y = l >> 8, x = l & 255;
        return (b << 16) + ((((y >> 3) << 5) + (x >> 3)) << 6) + ((y & 7) << 3) + (x & 7);
    } else if (PERM == 2) {
        int b = row >> 16, wv = row & 65535;
        int wid = wv >> 6, t = wv & 63;
        int wy = wid >> 5, wx = wid & 31;
        return (b << 16) + ((((wy << 3) + (t >> 3))) << 8) + (wx << 3) + (t & 7);
    }
    return row;
}

// ---------------- one-shot weight prep ----------------
// wbf: bf16 copies of the 4 GEMM weights. wT1/wT2: tap-major dwconv weights.
// br3: b_rel re-ordered to MFMA fragment order per (head, lane):
//      br3[h*4096 + lane*64 + (mt*16+nt*4+r)] = bf16(b_rel[h][mt*16+(lane>>4)*4+r][nt*16+(lane&15)])
__global__ __launch_bounds__(256) void convw_kernel(
    const float* __restrict__ a, const float* __restrict__ b,
    const float* __restrict__ c, const float* __restrict__ d,
    const float* __restrict__ cdw, const float* __restrict__ fdw,
    const float* __restrict__ brel,
    unsigned short* __restrict__ wbf, float* __restrict__ wT1, float* __restrict__ wT2,
    unsigned short* __restrict__ br3)
{
    int g = blockIdx.x * 256 + threadIdx.x;
    if (g < 259200) {
        float v;
        if      (g < 97200)  v = a[g];
        else if (g < 129600) v = b[g - 97200];
        else if (g < 194400) v = c[g - 129600];
        else                 v = d[g - 194400];
        wbf[g] = f2b(v);
    } else if (g < 265680) {
        int i = g - 259200;               // tap-major [9][180]
        int tap = i / 180, ch = i % 180;
        wT1[i] = cdw[ch * 9 + tap];
    } else if (g < 278640) {
        int i = g - 265680;               // [9][360]
        int tap = i / 360, ch = i % 360;
        wT2[i] = fdw[ch * 9 + tap];
    } else if (g < 303216) {
        int i = g - 278640;               // 6*4096 fragment-ordered bias
        int h = i >> 12;
        int rem = i & 4095;
        int lane = rem >> 6;
        int j = rem & 63;
        int mt = j >> 4, nt = (j >> 2) & 3, r = j & 3;
        int row = mt * 16 + (lane >> 4) * 4 + r;
        int col = nt * 16 + (lane & 15);
        br3[i] = f2b(brel[h * 4096 + row * 64 + col]);
    }
}

// ---------------- LayerNorm: one wave per token, vectorized (45 active lanes) ----------------
__device__ __forceinline__ void ld4(const float* p, float v[4]) {
    float4 t = *(const float4*)p; v[0]=t.x; v[1]=t.y; v[2]=t.z; v[3]=t.w;
}
__device__ __forceinline__ void ld4(const unsigned short* p, float v[4]) {
    ushort4 t = *(const ushort4*)p; v[0]=b2f(t.x); v[1]=b2f(t.y); v[2]=b2f(t.z); v[3]=b2f(t.w);
}

template <typename TIN>
__global__ __launch_bounds__(256) void ln_kernel(
    const TIN* __restrict__ x, const float* __restrict__ g,
    const float* __restrict__ bta, unsigned short* __restrict__ out)
{
    int wave = threadIdx.x >> 6, lane = threadIdx.x & 63;
    int tok = blockIdx.x * 4 + wave;
    const bool act = lane < 45;                 // 45*4 = 180 channels
    float v[4] = {0.f, 0.f, 0.f, 0.f};
    const TIN* row = x + (size_t)tok * CH;
    if (act) ld4(row + lane * 4, v);
    float s  = v[0] + v[1] + v[2] + v[3];
    float sq = v[0]*v[0] + v[1]*v[1] + v[2]*v[2] + v[3]*v[3];
    #pragma unroll
    for (int off = 32; off > 0; off >>= 1) {
        s  += __shfl_xor(s, off);
        sq += __shfl_xor(sq, off);
    }
    float mean = s * (1.f / CH);
    float var  = sq * (1.f / CH) - mean * mean;
    float rstd = rsqrtf(var + 1e-5f);
    if (act) {
        float4 gg = *(const float4*)&g[lane * 4];
        float4 bb = *(const float4*)&bta[lane * 4];
        unsigned int o0 = (unsigned int)f2b((v[0]-mean)*rstd*gg.x + bb.x)
                        | ((unsigned int)f2b((v[1]-mean)*rstd*gg.y + bb.y) << 16);
        unsigned int o1 = (unsigned int)f2b((v[2]-mean)*rstd*gg.z + bb.z)
                        | ((unsigned int)f2b((v[3]-mean)*rstd*gg.w + bb.w) << 16);
        *(uint2*)(out + (size_t)tok * CH + lane * 4) = make_uint2(o0, o1);
    }
}

// ---------------- generic MFMA GEMM, A-register-resident panel form ----------------
// One block owns a 128-row A panel (wave w: rows w*32..w*32+31). ALL A fragments are
// preloaded into registers ONCE (K is a template param -> fully static indexing), then
// the n-tile loop touches only B (L1/L2-resident, ~0.2MB) + MFMAs. A is fetched from
// HBM exactly once chip-wide. No LDS, no barriers. K-tail zeroed on BOTH operands.
__device__ __forceinline__ void stv(float* p, float v) { *p = v; }
__device__ __forceinline__ void stv(unsigned short* p, float v) { *p = f2b(v); }

__device__ __forceinline__ frag_ab ldg_frag(const unsigned short* p) {
    union { frag_ab f; uint2 u[2]; } t;
    t.u[0] = *(const uint2*)p;
    t.u[1] = *(const uint2*)(p + 4);
    return t.f;
}
__device__ __forceinline__ frag_ab ldg_frag_tail(const unsigned short* p, int kcol0, int K) {
    union { frag_ab f; unsigned short s[8]; } t;
    #pragma unroll
    for (int j = 0; j < 8; ++j)
        t.s[j] = (kcol0 + j < K) ? p[j] : (unsigned short)0;
    return t.f;
}

template <int KT, int ACT, bool HAS_BIAS, bool HAS_RES, int PERM, typename TOUT>
__global__ __launch_bounds__(256) void gemm_kernel(
    const unsigned short* __restrict__ X, int ldx,
    const unsigned short* __restrict__ Wt,
    const float* __restrict__ bias,
    const unsigned short* __restrict__ res, int ldr,
    TOUT* __restrict__ Y, int ldy,
    int N)
{
    constexpr int NCH  = KT / 32;            // full 32-wide k-chunks (180->5, 360->11)
    constexpr bool TAIL = (KT % 32) != 0;
    constexpr int NFR  = NCH + (TAIL ? 1 : 0);

    const int tid = threadIdx.x;
    const int wave = tid >> 6;
    const int lane = tid & 63;
    const int l16 = lane & 15;
    const int q = lane >> 4;
    const int m0 = blockIdx.x * 128;
    const int ktail0 = NCH * 32 + q * 8;

    // ---- preload ALL A fragments for this wave's 32 rows (static indices) ----
    frag_ab areg[2][NFR];
    {
        const unsigned short* aptr0 = X + (size_t)(m0 + wave * 32 + l16) * ldx + q * 8;
        const unsigned short* aptr1 = aptr0 + (size_t)16 * ldx;
        #pragma unroll
        for (int kc = 0; kc < NCH; ++kc) {
            areg[0][kc] = ldg_frag(aptr0 + kc * 32);
            areg[1][kc] = ldg_frag(aptr1 + kc * 32);
        }
        if (TAIL) {
            areg[0][NFR - 1] = ldg_frag_tail(aptr0 + NCH * 32, ktail0, KT);
            areg[1][NFR - 1] = ldg_frag_tail(aptr1 + NCH * 32, ktail0, KT);
        }
    }

    for (int n0 = 0; n0 < N; n0 += 64) {
        frag_cd acc[2][4];
        #pragma unroll
        for (int mb = 0; mb < 2; ++mb)
            #pragma unroll
            for (int nb = 0; nb < 4; ++nb)
                acc[mb][nb] = (frag_cd){0.f, 0.f, 0.f, 0.f};

        const unsigned short* bptr[4];
        #pragma unroll
        for (int nb = 0; nb < 4; ++nb)
            bptr[nb] = Wt + (size_t)(n0 + nb * 16 + l16) * KT + q * 8;

        #pragma unroll
        for (int kc = 0; kc < NCH; ++kc) {
            #pragma unroll
            for (int nb = 0; nb < 4; ++nb) {
                frag_ab b = ldg_frag(bptr[nb] + kc * 32);
                acc[0][nb] = __builtin_amdgcn_mfma_f32_16x16x32_bf16(areg[0][kc], b, acc[0][nb], 0, 0, 0);
                acc[1][nb] = __builtin_amdgcn_mfma_f32_16x16x32_bf16(areg[1][kc], b, acc[1][nb], 0, 0, 0);
            }
        }
        if (TAIL) {
            #pragma unroll
            for (int nb = 0; nb < 4; ++nb) {
                frag_ab b = ldg_frag_tail(bptr[nb] + NCH * 32, ktail0, KT);
                acc[0][nb] = __builtin_amdgcn_mfma_f32_16x16x32_bf16(areg[0][NFR - 1], b, acc[0][nb], 0, 0, 0);
                acc[1][nb] = __builtin_amdgcn_mfma_f32_16x16x32_bf16(areg[1][NFR - 1], b, acc[1][nb], 0, 0, 0);
            }
        }

        // ---- epilogue for this n-tile ----
        #pragma unroll
        for (int nb = 0; nb < 4; ++nb) {
            const int col = n0 + nb * 16 + l16;
            if (col < N) {
                float bv = 0.f;
                if (HAS_BIAS) bv = bias[col];
                #pragma unroll
                for (int mb = 0; mb < 2; ++mb) {
                    #pragma unroll
                    for (int r = 0; r < 4; ++r) {
                        int row = m0 + wave * 32 + mb * 16 + q * 4 + r;
                        int orow = perm_row<PERM>(row);
                        float v = acc[mb][nb][r] + bv;
                        if (ACT == 1) v = gelu_f(v);
                        if (HAS_RES) v += b2f(res[(size_t)orow * ldr + col]);
                        stv(&Y[(size_t)orow * ldy + col], v);
                    }
                }
            }
        }
    }
}

// ---------------- window attention: MFMA, one wave per (window, head) ----------------
// qkvw is WINDOW-ORDERED: row w64 = w*64 + t, cols [q:h*30+d][k:180+...][v:360+...]
// S = Q@K^T via mfma_f32_16x16x32_bf16; C/D layout col=lane&15, row=(lane>>4)*4+reg.
__global__ __launch_bounds__(64) void attn_kernel(
    const unsigned short* __restrict__ qkvw,
    const unsigned short* __restrict__ br3,
    unsigned short* __restrict__ attn_out)
{
    __shared__ unsigned short Pl[64][72];   // P bf16, stride 72 (144 B: 16B-aligned rows)
    __shared__ unsigned short VT[32][72];   // V^T bf16 [d][key], rows 30,31 zeroed
    const int blk = blockIdx.x;             // 0..12287
    const int h = blk % 6;
    const int w = blk / 6;
    const int lane = threadIdx.x;
    const int l16 = lane & 15;
    const int g4 = lane >> 4;
    const float scale = 0.18257418583505536f;  // 30^-0.5

    const unsigned short* base = qkvw + (size_t)w * (64 * 540) + h * 30;

    // ---- Q (A) and K (B) fragments straight from global (4B-aligned uint2 loads) ----
    frag_ab qf[4], kf[4];
    #pragma unroll
    for (int t = 0; t < 4; ++t) {
        const unsigned short* pq = base + (size_t)(t * 16 + l16) * 540 + g4 * 8;
        union { frag_ab f; uint2 u[2]; } tq, tk;
        tq.u[0] = *(const uint2*)pq;        tq.u[1] = *(const uint2*)(pq + 4);
        tk.u[0] = *(const uint2*)(pq + 180); tk.u[1] = *(const uint2*)(pq + 184);
        if (g4 == 3) { tk.f[6] = 0; tk.f[7] = 0; }   // zero K pad cols d=30,31
        qf[t] = tq.f; kf[t] = tk.f;
    }

    // ---- fragment-ordered bias (bf16, coalesced uint4 loads) ----
    unsigned int brw[32];
    {
        const unsigned short* bp = br3 + ((size_t)h << 12) + lane * 64;
        #pragma unroll
        for (int c2 = 0; c2 < 8; ++c2)
            *(uint4*)&brw[c2 * 4] = *(const uint4*)(bp + c2 * 8);
    }

    // ---- S = Q @ K^T : 16 MFMA ----
    frag_cd s[4][4];
    #pragma unroll
    for (int mt = 0; mt < 4; ++mt)
        #pragma unroll
        for (int nt = 0; nt < 4; ++nt)
            s[mt][nt] = (frag_cd){0.f, 0.f, 0.f, 0.f};
    #pragma unroll
    for (int mt = 0; mt < 4; ++mt)
        #pragma unroll
        for (int nt = 0; nt < 4; ++nt)
            s[mt][nt] = __builtin_amdgcn_mfma_f32_16x16x32_bf16(qf[mt], kf[nt], s[mt][nt], 0, 0, 0);

    // ---- stage V^T into LDS (overlaps with MFMA latency) ----
    {
        const unsigned short* pv = base + (size_t)lane * 540 + 360;
        #pragma unroll
        for (int d2 = 0; d2 < 15; ++d2) {
            unsigned int u = *(const unsigned int*)(pv + 2 * d2);
            VT[2 * d2][lane]     = (unsigned short)(u & 0xffffu);
            VT[2 * d2 + 1][lane] = (unsigned short)(u >> 16);
        }
        VT[30][lane] = 0; VT[31][lane] = 0;
    }

    // ---- bias + row softmax (unnormalized P -> LDS), inv kept per (mt,reg) ----
    float inv[4][4];
    #pragma unroll
    for (int mt = 0; mt < 4; ++mt) {
        #pragma unroll
        for (int r = 0; r < 4; ++r) {
            float a0 = s[mt][0][r] * scale + (((0 * 4 + r) & 1) ? bhi(brw[(mt * 16 + 0 + r) >> 1]) : blo(brw[(mt * 16 + 0 + r) >> 1]));
            float a1 = s[mt][1][r] * scale + (((1 * 4 + r) & 1) ? bhi(brw[(mt * 16 + 4 + r) >> 1]) : blo(brw[(mt * 16 + 4 + r) >> 1]));
            float a2 = s[mt][2][r] * scale + (((2 * 4 + r) & 1) ? bhi(brw[(mt * 16 + 8 + r) >> 1]) : blo(brw[(mt * 16 + 8 + r) >> 1]));
            float a3 = s[mt][3][r] * scale + (((3 * 4 + r) & 1) ? bhi(brw[(mt * 16 + 12 + r) >> 1]) : blo(brw[(mt * 16 + 12 + r) >> 1]));
            float m = fmaxf(fmaxf(a0, a1), fmaxf(a2, a3));
            m = fmaxf(m, __shfl_xor(m, 1));
            m = fmaxf(m, __shfl_xor(m, 2));
            m = fmaxf(m, __shfl_xor(m, 4));
            m = fmaxf(m, __shfl_xor(m, 8));
            float e0 = __expf(a0 - m), e1 = __expf(a1 - m);
            float e2 = __expf(a2 - m), e3 = __expf(a3 - m);
            float sum = e0 + e1 + e2 + e3;
            sum += __shfl_xor(sum, 1);
            sum += __shfl_xor(sum, 2);
            sum += __shfl_xor(sum, 4);
            sum += __shfl_xor(sum, 8);
            inv[mt][r] = 1.f / sum;
            int row = mt * 16 + g4 * 4 + r;
            Pl[row][l16]      = f2b(e0);
            Pl[row][16 + l16] = f2b(e1);
            Pl[row][32 + l16] = f2b(e2);
            Pl[row][48 + l16] = f2b(e3);
        }
    }
    __syncthreads();

    // ---- O = P @ V : A-frags from Pl, B-frags from VT, 16 MFMA ----
    frag_ab pf[4][2];
    #pragma unroll
    for (int mt = 0; mt < 4; ++mt)
        #pragma unroll
        for (int kt = 0; kt < 2; ++kt)
            pf[mt][kt] = *(const frag_ab*)&Pl[mt * 16 + l16][kt * 32 + g4 * 8];
    frag_ab vf[2][2];
    #pragma unroll
    for (int nt = 0; nt < 2; ++nt)
        #pragma unroll
        for (int kt = 0; kt < 2; ++kt)
            vf[nt][kt] = *(const frag_ab*)&VT[nt * 16 + l16][kt * 32 + g4 * 8];

    frag_cd o[4][2];
    #pragma unroll
    for (int mt = 0; mt < 4; ++mt)
        #pragma unroll
        for (int nt = 0; nt < 2; ++nt)
            o[mt][nt] = (frag_cd){0.f, 0.f, 0.f, 0.f};
    #pragma unroll
    for (int mt = 0; mt < 4; ++mt)
        #pragma unroll
        for (int nt = 0; nt < 2; ++nt)
            #pragma unroll
            for (int kt = 0; kt < 2; ++kt)
                o[mt][nt] = __builtin_amdgcn_mfma_f32_16x16x32_bf16(pf[mt][kt], vf[nt][kt], o[mt][nt], 0, 0, 0);

    // ---- epilogue: normalize rows by inv, store bf16 (cols 30,31 dropped) ----
    unsigned short* ob = attn_out + (size_t)w * (64 * CH) + h * 30;
    #pragma unroll
    for (int mt = 0; mt < 4; ++mt) {
        #pragma unroll
        for (int r = 0; r < 4; ++r) {
            int row = mt * 16 + g4 * 4 + r;
            float iv = inv[mt][r];
            unsigned short* op = ob + (size_t)row * CH;
            op[l16] = f2b(o[mt][0][r] * iv);
            if (l16 < 14) op[16 + l16] = f2b(o[mt][1][r] * iv);
        }
    }
}

// ---------------- depthwise 3x3 SAME conv, vectorized column-walk ----------------
template <int C, bool DO_GELU>
__global__ __launch_bounds__(256) void dwconv_kernel(
    const unsigned short* __restrict__ in, const float* __restrict__ wT,
    unsigned short* __restrict__ out)
{
    constexpr int NG = (C + 7) / 8;
    constexpr int TY = 8;
    int gid = blockIdx.x * 256 + threadIdx.x;
    int cg = gid % NG;
    int t  = gid / NG;
    int x  = t % IMG;
    int t2 = t / IMG;
    int yb = t2 & 31;
    int bi = t2 >> 5;
    if (bi >= BATCH) return;
    const int c0 = cg * 8;
    const int y0 = yb * TY;

    float w9[9][8];
    #pragma unroll
    for (int tp = 0; tp < 9; ++tp) {
        float4 wa = *(const float4*)&wT[tp * C + c0];
        float4 wb = *(const float4*)&wT[tp * C + c0 + 4];
        w9[tp][0]=wa.x; w9[tp][1]=wa.y; w9[tp][2]=wa.z; w9[tp][3]=wa.w;
        w9[tp][4]=wb.x; w9[tp][5]=wb.y; w9[tp][6]=wb.z; w9[tp][7]=wb.w;
    }

    unsigned int rr[3][3][4];

    auto load_row = [&](int y, unsigned int dst[3][4]) {
        if ((unsigned)y >= (unsigned)IMG) {
            #pragma unroll
            for (int cc = 0; cc < 3; ++cc)
                #pragma unroll
                for (int k = 0; k < 4; ++k) dst[cc][k] = 0u;
            return;
        }
        size_t base = ((size_t)((bi << 16) + (y << 8) + x)) * C + c0;
        #pragma unroll
        for (int cc = 0; cc < 3; ++cc) {
            int xx = x + cc - 1;
            if ((unsigned)xx >= (unsigned)IMG) {
                dst[cc][0] = dst[cc][1] = dst[cc][2] = dst[cc][3] = 0u;
                continue;
            }
            const unsigned short* p = in + base + (ptrdiff_t)(cc - 1) * C;
            uint2 u0 = *(const uint2*)p;
            uint2 u1 = *(const uint2*)(p + 4);
            dst[cc][0] = u0.x; dst[cc][1] = u0.y; dst[cc][2] = u1.x; dst[cc][3] = u1.y;
        }
    };

    load_row(y0 - 1, rr[0]);
    load_row(y0,     rr[1]);

    #pragma unroll
    for (int dy = 0; dy < TY; ++dy) {
        load_row(y0 + dy + 1, rr[(dy + 2) % 3]);
        float acc[8];
        #pragma unroll
        for (int j = 0; j < 8; ++j) acc[j] = 0.f;
        #pragma unroll
        for (int ky = 0; ky < 3; ++ky) {
            unsigned int (*row)[4] = rr[(dy + ky) % 3];
            #pragma unroll
            for (int kx = 0; kx < 3; ++kx) {
                const float* wp = w9[ky * 3 + kx];
                const unsigned int* u = row[kx];
                acc[0] += blo(u[0]) * wp[0];
                acc[1] += bhi(u[0]) * wp[1];
                acc[2] += blo(u[1]) * wp[2];
                acc[3] += bhi(u[1]) * wp[3];
                acc[4] += blo(u[2]) * wp[4];
                acc[5] += bhi(u[2]) * wp[5];
                acc[6] += blo(u[3]) * wp[6];
                acc[7] += bhi(u[3]) * wp[7];
            }
        }
        if (DO_GELU) {
            #pragma unroll
            for (int j = 0; j < 8; ++j) acc[j] = gelu_f(acc[j]);
        }
        size_t ob = ((size_t)((bi << 16) + ((y0 + dy) << 8) + x)) * C + c0;
        unsigned int o0 = (unsigned int)f2b(acc[0]) | ((unsigned int)f2b(acc[1]) << 16);
        unsigned int o1 = (unsigned int)f2b(acc[2]) | ((unsigned int)f2b(acc[3]) << 16);
        *(uint2*)(out + ob) = make_uint2(o0, o1);
        if (c0 + 8 <= C) {
            unsigned int o2 = (unsigned int)f2b(acc[4]) | ((unsigned int)f2b(acc[5]) << 16);
            unsigned int o3 = (unsigned int)f2b(acc[6]) | ((unsigned int)f2b(acc[7]) << 16);
            *(uint2*)(out + ob + 4) = make_uint2(o2, o3);
        }
    }
}

// ---------------- sum-pool over L per (b,c), ushort4 ----------------
__global__ __launch_bounds__(64) void pool_kernel(
    const unsigned short* __restrict__ cf, float* __restrict__ pooled)
{
    int t = threadIdx.x;
    if (t >= 45) return;
    int b = blockIdx.x >> 7;
    int chunk = blockIdx.x & 127;
    const unsigned short* base = cf + (size_t)(b * LTOK + chunk * 512) * CH + t * 4;
    float s0 = 0.f, s1 = 0.f, s2 = 0.f, s3 = 0.f;
    for (int i = 0; i < 512; ++i) {
        ushort4 v = *(const ushort4*)(base + (size_t)i * CH);
        s0 += b2f(v.x); s1 += b2f(v.y); s2 += b2f(v.z); s3 += b2f(v.w);
    }
    atomicAdd(&pooled[b * CH + t * 4 + 0], s0);
    atomicAdd(&pooled[b * CH + t * 4 + 1], s1);
    atomicAdd(&pooled[b * CH + t * 4 + 2], s2);
    atomicAdd(&pooled[b * CH + t * 4 + 3], s3);
}

// ---------------- channel gate ----------------
__global__ __launch_bounds__(256) void cm_kernel(
    const float* __restrict__ pooled, const float* __restrict__ w1,
    const float* __restrict__ w2, float* __restrict__ cm)
{
    __shared__ float p[BATCH][CH];
    __shared__ float g1[BATCH][22];
    int t = threadIdx.x;
    for (int idx = t; idx < BATCH * CH; idx += 256)
        p[idx / CH][idx % CH] = pooled[idx] * (1.f / (float)LTOK);
    __syncthreads();
    if (t < BATCH * 22) {
        int b = t / 22, u = t % 22;
        float s = 0.f;
        for (int c = 0; c < CH; ++c) s += p[b][c] * w1[u * CH + c];
        g1[b][u] = gelu_f(s);
    }
    __syncthreads();
    for (int idx = t; idx < BATCH * CH; idx += 256) {
        int b = idx / CH, c = idx % CH;
        float s = 0.f;
        for (int u = 0; u < 22; ++u) s += g1[b][u] * w2[c * 22 + u];
        cm[idx] = 1.f / (1.f + __expf(-s));
    }
}

// ---------------- residual 1, 4 channels/thread ----------------
__global__ __launch_bounds__(256) void resid_kernel(
    const float* __restrict__ x, const unsigned short* __restrict__ attn_feat,
    const unsigned short* __restrict__ conv_feat, const float* __restrict__ cm,
    unsigned short* __restrict__ x_mid)
{
    int gid = blockIdx.x * 256 + threadIdx.x;     // BL*CH/4 threads
    int c4 = gid % 45;
    int b = gid / (LTOK * 45);
    float4 xv = ((const float4*)x)[gid];
    ushort4 a = ((const ushort4*)attn_feat)[gid];
    ushort4 c = ((const ushort4*)conv_feat)[gid];
    float4 m = *(const float4*)&cm[b * CH + c4 * 4];
    unsigned int o0 = (unsigned int)f2b(xv.x + b2f(a.x) * m.x + b2f(c.x))
                    | ((unsigned int)f2b(xv.y + b2f(a.y) * m.y + b2f(c.y)) << 16);
    unsigned int o1 = (unsigned int)f2b(xv.z + b2f(a.z) * m.z + b2f(c.z))
                    | ((unsigned int)f2b(xv.w + b2f(a.w) * m.w + b2f(c.w)) << 16);
    ((uint2*)x_mid)[gid] = make_uint2(o0, o1);
}

// ---------------- launch ----------------
extern "C" void kernel_launch(void* const* d_in, const int* in_sizes, int n_in,
                              void* d_out, int out_size, void* d_ws, size_t ws_size,
                              hipStream_t stream)
{
    const float* x       = (const float*)d_in[0];
    const float* w_qkv   = (const float*)d_in[1];
    const float* b_rel   = (const float*)d_in[2];
    const float* w_proj  = (const float*)d_in[3];
    const float* b_proj  = (const float*)d_in[4];
    const float* conv_dw = (const float*)d_in[5];
    const float* cg_w1   = (const float*)d_in[6];
    const float* cg_w2   = (const float*)d_in[7];
    const float* ffn_w1  = (const float*)d_in[8];
    const float* ffn_dw  = (const float*)d_in[9];
    const float* ffn_w2  = (const float*)d_in[10];
    const float* n1_g    = (const float*)d_in[11];
    const float* n1_b    = (const float*)d_in[12];
    const float* n2_g    = (const float*)d_in[13];
    const float* n2_b    = (const float*)d_in[14];

    // ---- workspace layout (bytes), peak ~225.7 MiB ----
    char* ws = (char*)d_ws;
    unsigned short* n1        = (unsigned short*)(ws);                      // [0, 47.2MB)
    unsigned short* qkvw      = (unsigned short*)(ws + 47185920);           // [47.2, 188.7MB) window-ordered
    unsigned short* conv_feat = (unsigned short*)(ws + 188743680);          // [188.7, 235.9MB)
    unsigned short* attn_out  = (unsigned short*)(ws);                      // reuse n1 (window-ordered)
    unsigned short* attn_feat = (unsigned short*)(ws + 47185920);           // reuse qkv head (token order)
    unsigned short* x_mid     = (unsigned short*)(ws + 94371840);           // reuse qkv mid
    unsigned short* n2        = (unsigned short*)(ws + 141557760);          // reuse qkv tail
    unsigned short* h         = (unsigned short*)(ws);                      // [0, 94.4MB)
    unsigned short* h_s       = (unsigned short*)(ws + 141557760);          // [141.6, 235.9MB)
    float*          pooled    = (float*)(ws + 235929600);                   // 1440 B
    float*          cmv       = (float*)(ws + 235931040);                   // 1440 B
    unsigned short* wbf       = (unsigned short*)(ws + 235932480);          // 518,400 B
    float*          wT1       = (float*)(ws + 236450880);                   // 25,920 B
    float*          wT2       = (float*)(ws + 236476800);                   // 51,840 B
    unsigned short* br3       = (unsigned short*)(ws + 236528640);          // 49,152 B
    unsigned short* wqkv_b  = wbf;
    unsigned short* wproj_b = wbf + 97200;
    unsigned short* wffn1_b = wbf + 129600;
    unsigned short* wffn2_b = wbf + 194400;
    float* out = (float*)d_out;

    hipMemsetAsync(pooled, 0, 2880, stream);

    // 0. weight prep (incl. fragment-ordered bf16 b_rel)
    convw_kernel<<<1185, 256, 0, stream>>>(w_qkv, w_proj, ffn_w1, ffn_w2,
                                           conv_dw, ffn_dw, b_rel, wbf, wT1, wT2, br3);
    // 1. LN1: x(fp32) -> n1(bf16)
    ln_kernel<float><<<BL / 4, 256, 0, stream>>>(x, n1_g, n1_b, n1);
    // 2. qkvw = n1 @ w_qkv^T, rows stored window-ordered (PERM=1)
    gemm_kernel<180, 0, false, false, 1, unsigned short><<<BL / 128, 256, 0, stream>>>(
        n1, CH, wqkv_b, nullptr, nullptr, 0, qkvw, 540, 540);
    // 3. conv branch: gelu(dwconv3x3(n1)) -> conv_feat
    dwconv_kernel<CH, true><<<1472, 256, 0, stream>>>(n1, wT1, conv_feat);
    // 4. pooled = sum_L conv_feat
    pool_kernel<<<BATCH * 128, 64, 0, stream>>>(conv_feat, pooled);
    // 5. cm
    cm_kernel<<<1, 256, 0, stream>>>(pooled, cg_w1, cg_w2, cmv);
    // 6. window attention (MFMA): one wave per (window, head)
    attn_kernel<<<2048 * 6, 64, 0, stream>>>(qkvw, br3, attn_out);
    // 7. attn_feat = attn_out @ w_proj^T + b_proj; X window-ordered, Y token order (PERM=2)
    gemm_kernel<180, 0, true, false, 2, unsigned short><<<BL / 128, 256, 0, stream>>>(
        attn_out, CH, wproj_b, b_proj, nullptr, 0, attn_feat, CH, CH);
    // 8. x_mid = x + attn_feat*cm + conv_feat  (bf16)
    resid_kernel<<<(BL * CH / 4) / 256, 256, 0, stream>>>(x, attn_feat, conv_feat, cmv, x_mid);
    // 9. LN2
    ln_kernel<unsigned short><<<BL / 4, 256, 0, stream>>>(x_mid, n2_g, n2_b, n2);
    // 10. h = gelu(n2 @ ffn_w1^T)
    gemm_kernel<180, 1, false, false, 0, unsigned short><<<BL / 128, 256, 0, stream>>>(
        n2, CH, wffn1_b, nullptr, nullptr, 0, h, HDF, HDF);
    // 11. h_s = dwconv3x3(h)
    dwconv_kernel<HDF, false><<<2880, 256, 0, stream>>>(h, wT2, h_s);
    // 12. out(fp32) = x_mid + h_s @ ffn_w2^T
    gemm_kernel<360, 0, false, true, 0, float><<<BL / 128, 256, 0, stream>>>(
        h_s, HDF, wffn2_b, nullptr, x_mid, CH, out, CH, CH);
}

// Round 6
// 915.535 us; speedup vs baseline: 1.1488x; 1.0389x over previous
//
#include <hip/hip_runtime.h>
#include <hip/hip_bf16.h>
#include <math.h>

// ---------------- constants (problem is fixed-shape) ----------------
// B=2, H=W=256, L=65536, C=180, NH=6, hd=30, WS=8, hd_ffn=360
// I/O dtype: fp32 (per reference). Internals: bf16 (MFMA), fp32 accum.
#define BATCH 2
#define IMG 256
#define LTOK 65536
#define CH 180
#define BL (BATCH * LTOK)            // 131072 tokens
#define HDF 360

using frag_ab = __attribute__((ext_vector_type(8))) short;   // 8 bf16 in 4 VGPRs
using frag_cd = __attribute__((ext_vector_type(4))) float;   // 4 f32 acc

__device__ __forceinline__ float b2f(unsigned short u) {
    union { unsigned int i; float f; } v; v.i = ((unsigned int)u) << 16; return v.f;
}
__device__ __forceinline__ float blo(unsigned int u) {
    union { unsigned int i; float f; } v; v.i = u << 16; return v.f;
}
__device__ __forceinline__ float bhi(unsigned int u) {
    union { unsigned int i; float f; } v; v.i = u & 0xffff0000u; return v.f;
}
__device__ __forceinline__ unsigned short f2b(float f) {
    union { float f; unsigned int i; } v; v.f = f;
    unsigned int x = v.i;
    unsigned int r = (x + 0x7fffu + ((x >> 16) & 1u)) >> 16;   // RNE
    return (unsigned short)r;
}
__device__ __forceinline__ float gelu_f(float x) {
    return 0.5f * x * (1.0f + erff(x * 0.70710678118654752f));
}

// row-index permutations for window attention, folded into GEMM epilogues.
// PERM=2: window-order row -> token-order row.
template <int PERM>
__device__ __forceinline__ int perm_row(int row) {
    if (PERM == 1) {
        int b = row >> 16, l = row & 65535;
        int y = l >> 8, x = l & 255;
        return (b << 16) + ((((y >> 3) << 5) + (x >> 3)) << 6) + ((y & 7) << 3) + (x & 7);
    } else if (PERM == 2) {
        int b = row >> 16, wv = row & 65535;
        int wid = wv >> 6, t = wv & 63;
        int wy = wid >> 5, wx = wid & 31;
        return (b << 16) + ((((wy << 3) + (t >> 3))) << 8) + (wx << 3) + (t & 7);
    }
    return row;
}

// ---------------- one-shot weight prep ----------------
// wbf: bf16 copies of the 4 GEMM weights. wT1/wT2: tap-major dwconv weights.
// br4: b_rel in per-thread fragment order for the fused attn (1-mt form):
//      br4[h*4096 + tid*16 + nt*4 + r] = bf16(b_rel[h][(tid>>6)*16+((tid>>4)&3)*4+r][nt*16+(tid&15)])
__global__ __launch_bounds__(256) void convw_kernel(
    const float* __restrict__ a, const float* __restrict__ b,
    const float* __restrict__ c, const float* __restrict__ d,
    const float* __restrict__ cdw, const float* __restrict__ fdw,
    const float* __restrict__ brel,
    unsigned short* __restrict__ wbf, float* __restrict__ wT1, float* __restrict__ wT2,
    unsigned short* __restrict__ br4)
{
    int g = blockIdx.x * 256 + threadIdx.x;
    if (g < 259200) {
        float v;
        if      (g < 97200)  v = a[g];
        else if (g < 129600) v = b[g - 97200];
        else if (g < 194400) v = c[g - 129600];
        else                 v = d[g - 194400];
        wbf[g] = f2b(v);
    } else if (g < 265680) {
        int i = g - 259200;               // tap-major [9][180]
        int tap = i / 180, ch = i % 180;
        wT1[i] = cdw[ch * 9 + tap];
    } else if (g < 278640) {
        int i = g - 265680;               // [9][360]
        int tap = i / 360, ch = i % 360;
        wT2[i] = fdw[ch * 9 + tap];
    } else if (g < 303216) {
        int i = g - 278640;               // 6*256*16 per-thread-ordered bias
        int h = i >> 12;
        int rem = i & 4095;
        int tid = rem >> 4;
        int j = rem & 15;
        int nt = j >> 2, r = j & 3;
        int w = tid >> 6, q = (tid >> 4) & 3, l16 = tid & 15;
        int row = w * 16 + q * 4 + r;
        int col = nt * 16 + l16;
        br4[i] = f2b(brel[h * 4096 + row * 64 + col]);
    }
}

// ---------------- LayerNorm: one wave per token, vectorized (45 active lanes) ----------------
__device__ __forceinline__ void ld4(const float* p, float v[4]) {
    float4 t = *(const float4*)p; v[0]=t.x; v[1]=t.y; v[2]=t.z; v[3]=t.w;
}

template <typename TIN>
__global__ __launch_bounds__(256) void ln_kernel(
    const TIN* __restrict__ x, const float* __restrict__ g,
    const float* __restrict__ bta, unsigned short* __restrict__ out)
{
    int wave = threadIdx.x >> 6, lane = threadIdx.x & 63;
    int tok = blockIdx.x * 4 + wave;
    const bool act = lane < 45;                 // 45*4 = 180 channels
    float v[4] = {0.f, 0.f, 0.f, 0.f};
    const TIN* row = x + (size_t)tok * CH;
    if (act) ld4(row + lane * 4, v);
    float s  = v[0] + v[1] + v[2] + v[3];
    float sq = v[0]*v[0] + v[1]*v[1] + v[2]*v[2] + v[3]*v[3];
    #pragma unroll
    for (int off = 32; off > 0; off >>= 1) {
        s  += __shfl_xor(s, off);
        sq += __shfl_xor(sq, off);
    }
    float mean = s * (1.f / CH);
    float var  = sq * (1.f / CH) - mean * mean;
    float rstd = rsqrtf(var + 1e-5f);
    if (act) {
        float4 gg = *(const float4*)&g[lane * 4];
        float4 bb = *(const float4*)&bta[lane * 4];
        unsigned int o0 = (unsigned int)f2b((v[0]-mean)*rstd*gg.x + bb.x)
                        | ((unsigned int)f2b((v[1]-mean)*rstd*gg.y + bb.y) << 16);
        unsigned int o1 = (unsigned int)f2b((v[2]-mean)*rstd*gg.z + bb.z)
                        | ((unsigned int)f2b((v[3]-mean)*rstd*gg.w + bb.w) << 16);
        *(uint2*)(out + (size_t)tok * CH + lane * 4) = make_uint2(o0, o1);
    }
}

// ---------------- generic MFMA GEMM, A-register-resident panel form ----------------
__device__ __forceinline__ void stv(float* p, float v) { *p = v; }
__device__ __forceinline__ void stv(unsigned short* p, float v) { *p = f2b(v); }

__device__ __forceinline__ frag_ab ldg_frag(const unsigned short* p) {
    union { frag_ab f; uint2 u[2]; } t;
    t.u[0] = *(const uint2*)p;
    t.u[1] = *(const uint2*)(p + 4);
    return t.f;
}
__device__ __forceinline__ frag_ab ldg_frag_tail(const unsigned short* p, int kcol0, int K) {
    union { frag_ab f; unsigned short s[8]; } t;
    #pragma unroll
    for (int j = 0; j < 8; ++j)
        t.s[j] = (kcol0 + j < K) ? p[j] : (unsigned short)0;
    return t.f;
}

template <int KT, int ACT, bool HAS_BIAS, bool HAS_RES, int PERM, typename TOUT>
__global__ __launch_bounds__(256) void gemm_kernel(
    const unsigned short* __restrict__ X, int ldx,
    const unsigned short* __restrict__ Wt,
    const float* __restrict__ bias,
    const unsigned short* __restrict__ res, int ldr,
    TOUT* __restrict__ Y, int ldy,
    int N)
{
    constexpr int NCH  = KT / 32;
    constexpr bool TAIL = (KT % 32) != 0;
    constexpr int NFR  = NCH + (TAIL ? 1 : 0);

    const int tid = threadIdx.x;
    const int wave = tid >> 6;
    const int lane = tid & 63;
    const int l16 = lane & 15;
    const int q = lane >> 4;
    const int m0 = blockIdx.x * 128;
    const int ktail0 = NCH * 32 + q * 8;

    frag_ab areg[2][NFR];
    {
        const unsigned short* aptr0 = X + (size_t)(m0 + wave * 32 + l16) * ldx + q * 8;
        const unsigned short* aptr1 = aptr0 + (size_t)16 * ldx;
        #pragma unroll
        for (int kc = 0; kc < NCH; ++kc) {
            areg[0][kc] = ldg_frag(aptr0 + kc * 32);
            areg[1][kc] = ldg_frag(aptr1 + kc * 32);
        }
        if (TAIL) {
            areg[0][NFR - 1] = ldg_frag_tail(aptr0 + NCH * 32, ktail0, KT);
            areg[1][NFR - 1] = ldg_frag_tail(aptr1 + NCH * 32, ktail0, KT);
        }
    }

    for (int n0 = 0; n0 < N; n0 += 64) {
        frag_cd acc[2][4];
        #pragma unroll
        for (int mb = 0; mb < 2; ++mb)
            #pragma unroll
            for (int nb = 0; nb < 4; ++nb)
                acc[mb][nb] = (frag_cd){0.f, 0.f, 0.f, 0.f};

        const unsigned short* bptr[4];
        #pragma unroll
        for (int nb = 0; nb < 4; ++nb)
            bptr[nb] = Wt + (size_t)(n0 + nb * 16 + l16) * KT + q * 8;

        #pragma unroll
        for (int kc = 0; kc < NCH; ++kc) {
            #pragma unroll
            for (int nb = 0; nb < 4; ++nb) {
                frag_ab b = ldg_frag(bptr[nb] + kc * 32);
                acc[0][nb] = __builtin_amdgcn_mfma_f32_16x16x32_bf16(areg[0][kc], b, acc[0][nb], 0, 0, 0);
                acc[1][nb] = __builtin_amdgcn_mfma_f32_16x16x32_bf16(areg[1][kc], b, acc[1][nb], 0, 0, 0);
            }
        }
        if (TAIL) {
            #pragma unroll
            for (int nb = 0; nb < 4; ++nb) {
                frag_ab b = ldg_frag_tail(bptr[nb] + NCH * 32, ktail0, KT);
                acc[0][nb] = __builtin_amdgcn_mfma_f32_16x16x32_bf16(areg[0][NFR - 1], b, acc[0][nb], 0, 0, 0);
                acc[1][nb] = __builtin_amdgcn_mfma_f32_16x16x32_bf16(areg[1][NFR - 1], b, acc[1][nb], 0, 0, 0);
            }
        }

        #pragma unroll
        for (int nb = 0; nb < 4; ++nb) {
            const int col = n0 + nb * 16 + l16;
            if (col < N) {
                float bv = 0.f;
                if (HAS_BIAS) bv = bias[col];
                #pragma unroll
                for (int mb = 0; mb < 2; ++mb) {
                    #pragma unroll
                    for (int r = 0; r < 4; ++r) {
                        int row = m0 + wave * 32 + mb * 16 + q * 4 + r;
                        int orow = perm_row<PERM>(row);
                        float v = acc[mb][nb][r] + bv;
                        if (ACT == 1) v = gelu_f(v);
                        if (HAS_RES) v += b2f(res[(size_t)orow * ldr + col]);
                        stv(&Y[(size_t)orow * ldy + col], v);
                    }
                }
            }
        }
    }
}

// ---------------- FUSED qkv-projection + window attention ----------------
// One block (4 waves) per window; wave w owns rows w*16..w*16+15 (queries AND keys).
// A-frags (n1, K=180) preloaded once. Per head h:
//   proj: Q/K/V = n1 @ Wqkv rows [s*180+h*30 .. +29], C/D scattered to LDS
//         (Qlds per-wave [16][40]; Klds shared [64][40]; VT shared [32][72] transposed;
//          d=30,31 zeroed via the l16>=14 guard on the nt=1 half)
//   S = Q@K^T (1 mt x 4 nt, K=32), softmax per row with shfl over l16,
//   P -> Pl (per-wave), O = P@V, 1/sum folded into epilogue.
// Same MFMA conventions as the verified gemm/attn kernels. qkvw intermediate ELIMINATED.
__global__ __launch_bounds__(256) void qkvattn_kernel(
    const unsigned short* __restrict__ n1,
    const unsigned short* __restrict__ wqkv,
    const unsigned short* __restrict__ br4,
    unsigned short* __restrict__ attn_out)
{
    __shared__ unsigned short Klds[64][40];      // K[key][d], d 30,31 zero
    __shared__ unsigned short VT[32][72];        // V^T[d][key], rows 30,31 zero
    __shared__ unsigned short Qlds[4][16][40];   // per-wave Q[row][d]
    __shared__ unsigned short Pl[4][16][72];     // per-wave P[row][key]

    const int blk = blockIdx.x;                  // window id, 0..2047
    const int b = blk >> 10;
    const int wid = blk & 1023;
    const int wy = wid >> 5, wx = wid & 31;
    const int tid = threadIdx.x;
    const int wave = tid >> 6;
    const int lane = tid & 63;
    const int l16 = lane & 15;
    const int q = lane >> 4;
    const float scale = 0.18257418583505536f;    // 30^-0.5

    // ---- A fragments: this lane's token row = window position wave*16+l16 ----
    frag_ab areg[6];
    {
        int t = wave * 16 + l16;
        size_t grow = ((size_t)b << 16) + (size_t)((wy * 8 + (t >> 3)) << 8) + wx * 8 + (t & 7);
        const unsigned short* ap = n1 + grow * CH + q * 8;
        #pragma unroll
        for (int kc = 0; kc < 5; ++kc) areg[kc] = ldg_frag(ap + kc * 32);
        areg[5] = ldg_frag_tail(ap + 160, 160 + q * 8, CH);
    }

    for (int h = 0; h < 6; ++h) {
        // ---- bias fragment (16 bf16 = 2 uint4, per-thread ordered) ----
        unsigned int brw[8];
        {
            const unsigned short* bp = br4 + ((size_t)h << 12) + tid * 16;
            *(uint4*)&brw[0] = *(const uint4*)bp;
            *(uint4*)&brw[4] = *(const uint4*)(bp + 8);
        }

        // ---- projections: s=0 Q, 1 K, 2 V; nt folded as row / row+16 ----
        #pragma unroll
        for (int s = 0; s < 3; ++s) {
            const unsigned short* wp0 = wqkv + (size_t)(s * 180 + h * 30 + l16) * CH + q * 8;
            const unsigned short* wp1 = wp0 + (size_t)16 * CH;
            frag_cd ac0 = (frag_cd){0.f, 0.f, 0.f, 0.f};
            frag_cd ac1 = (frag_cd){0.f, 0.f, 0.f, 0.f};
            #pragma unroll
            for (int kc = 0; kc < 5; ++kc) {
                frag_ab b0 = ldg_frag(wp0 + kc * 32);
                frag_ab b1 = ldg_frag(wp1 + kc * 32);
                ac0 = __builtin_amdgcn_mfma_f32_16x16x32_bf16(areg[kc], b0, ac0, 0, 0, 0);
                ac1 = __builtin_amdgcn_mfma_f32_16x16x32_bf16(areg[kc], b1, ac1, 0, 0, 0);
            }
            {
                frag_ab b0 = ldg_frag_tail(wp0 + 160, 160 + q * 8, CH);
                frag_ab b1 = ldg_frag_tail(wp1 + 160, 160 + q * 8, CH);
                ac0 = __builtin_amdgcn_mfma_f32_16x16x32_bf16(areg[5], b0, ac0, 0, 0, 0);
                ac1 = __builtin_amdgcn_mfma_f32_16x16x32_bf16(areg[5], b1, ac1, 0, 0, 0);
            }
            // scatter C/D (col=l16, row=q*4+r) to LDS; d=16+l16 zeroed for l16>=14
            #pragma unroll
            for (int r = 0; r < 4; ++r) {
                unsigned short v0 = f2b(ac0[r]);
                unsigned short v1 = (l16 >= 14) ? (unsigned short)0 : f2b(ac1[r]);
                int rr = wave * 16 + q * 4 + r;
                if (s == 0) {
                    Qlds[wave][q * 4 + r][l16]      = v0;
                    Qlds[wave][q * 4 + r][16 + l16] = v1;
                } else if (s == 1) {
                    Klds[rr][l16]      = v0;
                    Klds[rr][16 + l16] = v1;
                } else {
                    VT[l16][rr]      = v0;
                    VT[16 + l16][rr] = v1;
                }
            }
        }
        __syncthreads();

        // ---- S = Q @ K^T (K=32 covers d=0..31) ----
        frag_ab qf = *(const frag_ab*)&Qlds[wave][l16][q * 8];
        frag_cd s4[4];
        #pragma unroll
        for (int nt = 0; nt < 4; ++nt) {
            frag_ab kf = *(const frag_ab*)&Klds[nt * 16 + l16][q * 8];
            s4[nt] = __builtin_amdgcn_mfma_f32_16x16x32_bf16(
                qf, kf, (frag_cd){0.f, 0.f, 0.f, 0.f}, 0, 0, 0);
        }

        // ---- softmax per row q*4+r (reduce 4 nt in-reg + shfl over l16) ----
        float inv[4];
        #pragma unroll
        for (int r = 0; r < 4; ++r) {
            float a0 = s4[0][r] * scale + ((r & 1) ? bhi(brw[0 + (r >> 1)]) : blo(brw[0 + (r >> 1)]));
            float a1 = s4[1][r] * scale + ((r & 1) ? bhi(brw[2 + (r >> 1)]) : blo(brw[2 + (r >> 1)]));
            float a2 = s4[2][r] * scale + ((r & 1) ? bhi(brw[4 + (r >> 1)]) : blo(brw[4 + (r >> 1)]));
            float a3 = s4[3][r] * scale + ((r & 1) ? bhi(brw[6 + (r >> 1)]) : blo(brw[6 + (r >> 1)]));
            float m = fmaxf(fmaxf(a0, a1), fmaxf(a2, a3));
            m = fmaxf(m, __shfl_xor(m, 1));
            m = fmaxf(m, __shfl_xor(m, 2));
            m = fmaxf(m, __shfl_xor(m, 4));
            m = fmaxf(m, __shfl_xor(m, 8));
            float e0 = __expf(a0 - m), e1 = __expf(a1 - m);
            float e2 = __expf(a2 - m), e3 = __expf(a3 - m);
            float sum = e0 + e1 + e2 + e3;
            sum += __shfl_xor(sum, 1);
            sum += __shfl_xor(sum, 2);
            sum += __shfl_xor(sum, 4);
            sum += __shfl_xor(sum, 8);
            inv[r] = 1.f / sum;
            int pr = q * 4 + r;
            Pl[wave][pr][l16]      = f2b(e0);
            Pl[wave][pr][16 + l16] = f2b(e1);
            Pl[wave][pr][32 + l16] = f2b(e2);
            Pl[wave][pr][48 + l16] = f2b(e3);
        }
        __syncthreads();

        // ---- O = P @ V ----
        frag_ab pf0 = *(const frag_ab*)&Pl[wave][l16][q * 8];
        frag_ab pf1 = *(const frag_ab*)&Pl[wave][l16][32 + q * 8];
        frag_ab v00 = *(const frag_ab*)&VT[l16][q * 8];
        frag_ab v01 = *(const frag_ab*)&VT[l16][32 + q * 8];
        frag_ab v10 = *(const frag_ab*)&VT[16 + l16][q * 8];
        frag_ab v11 = *(const frag_ab*)&VT[16 + l16][32 + q * 8];
        frag_cd o0 = (frag_cd){0.f, 0.f, 0.f, 0.f};
        frag_cd o1 = (frag_cd){0.f, 0.f, 0.f, 0.f};
        o0 = __builtin_amdgcn_mfma_f32_16x16x32_bf16(pf0, v00, o0, 0, 0, 0);
        o0 = __builtin_amdgcn_mfma_f32_16x16x32_bf16(pf1, v01, o0, 0, 0, 0);
        o1 = __builtin_amdgcn_mfma_f32_16x16x32_bf16(pf0, v10, o1, 0, 0, 0);
        o1 = __builtin_amdgcn_mfma_f32_16x16x32_bf16(pf1, v11, o1, 0, 0, 0);

        // ---- epilogue: window-ordered rows, cols 30,31 dropped ----
        unsigned short* ob = attn_out + ((size_t)blk * 64 + wave * 16) * CH + h * 30;
        #pragma unroll
        for (int r = 0; r < 4; ++r) {
            float iv = inv[r];
            unsigned short* op = ob + (size_t)(q * 4 + r) * CH;
            op[l16] = f2b(o0[r] * iv);
            if (l16 < 14) op[16 + l16] = f2b(o1[r] * iv);
        }
        __syncthreads();   // before next head overwrites Klds/VT
    }
}

// ---------------- depthwise 3x3 SAME conv, vectorized column-walk ----------------
template <int C, bool DO_GELU>
__global__ __launch_bounds__(256) void dwconv_kernel(
    const unsigned short* __restrict__ in, const float* __restrict__ wT,
    unsigned short* __restrict__ out)
{
    constexpr int NG = (C + 7) / 8;
    constexpr int TY = 8;
    int gid = blockIdx.x * 256 + threadIdx.x;
    int cg = gid % NG;
    int t  = gid / NG;
    int x  = t % IMG;
    int t2 = t / IMG;
    int yb = t2 & 31;
    int bi = t2 >> 5;
    if (bi >= BATCH) return;
    const int c0 = cg * 8;
    const int y0 = yb * TY;

    float w9[9][8];
    #pragma unroll
    for (int tp = 0; tp < 9; ++tp) {
        float4 wa = *(const float4*)&wT[tp * C + c0];
        float4 wb = *(const float4*)&wT[tp * C + c0 + 4];
        w9[tp][0]=wa.x; w9[tp][1]=wa.y; w9[tp][2]=wa.z; w9[tp][3]=wa.w;
        w9[tp][4]=wb.x; w9[tp][5]=wb.y; w9[tp][6]=wb.z; w9[tp][7]=wb.w;
    }

    unsigned int rr[3][3][4];

    auto load_row = [&](int y, unsigned int dst[3][4]) {
        if ((unsigned)y >= (unsigned)IMG) {
            #pragma unroll
            for (int cc = 0; cc < 3; ++cc)
                #pragma unroll
                for (int k = 0; k < 4; ++k) dst[cc][k] = 0u;
            return;
        }
        size_t base = ((size_t)((bi << 16) + (y << 8) + x)) * C + c0;
        #pragma unroll
        for (int cc = 0; cc < 3; ++cc) {
            int xx = x + cc - 1;
            if ((unsigned)xx >= (unsigned)IMG) {
                dst[cc][0] = dst[cc][1] = dst[cc][2] = dst[cc][3] = 0u;
                continue;
            }
            const unsigned short* p = in + base + (ptrdiff_t)(cc - 1) * C;
            uint2 u0 = *(const uint2*)p;
            uint2 u1 = *(const uint2*)(p + 4);
            dst[cc][0] = u0.x; dst[cc][1] = u0.y; dst[cc][2] = u1.x; dst[cc][3] = u1.y;
        }
    };

    load_row(y0 - 1, rr[0]);
    load_row(y0,     rr[1]);

    #pragma unroll
    for (int dy = 0; dy < TY; ++dy) {
        load_row(y0 + dy + 1, rr[(dy + 2) % 3]);
        float acc[8];
        #pragma unroll
        for (int j = 0; j < 8; ++j) acc[j] = 0.f;
        #pragma unroll
        for (int ky = 0; ky < 3; ++ky) {
            unsigned int (*row)[4] = rr[(dy + ky) % 3];
            #pragma unroll
            for (int kx = 0; kx < 3; ++kx) {
                const float* wp = w9[ky * 3 + kx];
                const unsigned int* u = row[kx];
                acc[0] += blo(u[0]) * wp[0];
                acc[1] += bhi(u[0]) * wp[1];
                acc[2] += blo(u[1]) * wp[2];
                acc[3] += bhi(u[1]) * wp[3];
                acc[4] += blo(u[2]) * wp[4];
                acc[5] += bhi(u[2]) * wp[5];
                acc[6] += blo(u[3]) * wp[6];
                acc[7] += bhi(u[3]) * wp[7];
            }
        }
        if (DO_GELU) {
            #pragma unroll
            for (int j = 0; j < 8; ++j) acc[j] = gelu_f(acc[j]);
        }
        size_t ob = ((size_t)((bi << 16) + ((y0 + dy) << 8) + x)) * C + c0;
        unsigned int o0 = (unsigned int)f2b(acc[0]) | ((unsigned int)f2b(acc[1]) << 16);
        unsigned int o1 = (unsigned int)f2b(acc[2]) | ((unsigned int)f2b(acc[3]) << 16);
        *(uint2*)(out + ob) = make_uint2(o0, o1);
        if (c0 + 8 <= C) {
            unsigned int o2 = (unsigned int)f2b(acc[4]) | ((unsigned int)f2b(acc[5]) << 16);
            unsigned int o3 = (unsigned int)f2b(acc[6]) | ((unsigned int)f2b(acc[7]) << 16);
            *(uint2*)(out + ob + 4) = make_uint2(o2, o3);
        }
    }
}

// ---------------- sum-pool over L per (b,c), ushort4 ----------------
__global__ __launch_bounds__(64) void pool_kernel(
    const unsigned short* __restrict__ cf, float* __restrict__ pooled)
{
    int t = threadIdx.x;
    if (t >= 45) return;
    int b = blockIdx.x >> 7;
    int chunk = blockIdx.x & 127;
    const unsigned short* base = cf + (size_t)(b * LTOK + chunk * 512) * CH + t * 4;
    float s0 = 0.f, s1 = 0.f, s2 = 0.f, s3 = 0.f;
    for (int i = 0; i < 512; ++i) {
        ushort4 v = *(const ushort4*)(base + (size_t)i * CH);
        s0 += b2f(v.x); s1 += b2f(v.y); s2 += b2f(v.z); s3 += b2f(v.w);
    }
    atomicAdd(&pooled[b * CH + t * 4 + 0], s0);
    atomicAdd(&pooled[b * CH + t * 4 + 1], s1);
    atomicAdd(&pooled[b * CH + t * 4 + 2], s2);
    atomicAdd(&pooled[b * CH + t * 4 + 3], s3);
}

// ---------------- channel gate ----------------
__global__ __launch_bounds__(256) void cm_kernel(
    const float* __restrict__ pooled, const float* __restrict__ w1,
    const float* __restrict__ w2, float* __restrict__ cm)
{
    __shared__ float p[BATCH][CH];
    __shared__ float g1[BATCH][22];
    int t = threadIdx.x;
    for (int idx = t; idx < BATCH * CH; idx += 256)
        p[idx / CH][idx % CH] = pooled[idx] * (1.f / (float)LTOK);
    __syncthreads();
    if (t < BATCH * 22) {
        int b = t / 22, u = t % 22;
        float s = 0.f;
        for (int c = 0; c < CH; ++c) s += p[b][c] * w1[u * CH + c];
        g1[b][u] = gelu_f(s);
    }
    __syncthreads();
    for (int idx = t; idx < BATCH * CH; idx += 256) {
        int b = idx / CH, c = idx % CH;
        float s = 0.f;
        for (int u = 0; u < 22; ++u) s += g1[b][u] * w2[c * 22 + u];
        cm[idx] = 1.f / (1.f + __expf(-s));
    }
}

// ---------------- fused residual-1 + LN2: one wave per token ----------------
// x_mid = x + attn_feat*cm + conv_feat (bf16-rounded), then LN over the rounded row -> n2.
__global__ __launch_bounds__(256) void resid_ln2_kernel(
    const float* __restrict__ x, const unsigned short* __restrict__ attn_feat,
    const unsigned short* __restrict__ conv_feat, const float* __restrict__ cm,
    const float* __restrict__ g, const float* __restrict__ bta,
    unsigned short* __restrict__ x_mid, unsigned short* __restrict__ n2)
{
    int wave = threadIdx.x >> 6, lane = threadIdx.x & 63;
    int tok = blockIdx.x * 4 + wave;
    const bool act = lane < 45;
    float v[4] = {0.f, 0.f, 0.f, 0.f};
    if (act) {
        size_t base = (size_t)tok * CH + lane * 4;
        float4 xv = *(const float4*)&x[base];
        ushort4 a = *(const ushort4*)&attn_feat[base];
        ushort4 c = *(const ushort4*)&conv_feat[base];
        int b = tok >> 16;
        float4 m = *(const float4*)&cm[b * CH + lane * 4];
        unsigned short u0 = f2b(xv.x + b2f(a.x) * m.x + b2f(c.x));
        unsigned short u1 = f2b(xv.y + b2f(a.y) * m.y + b2f(c.y));
        unsigned short u2 = f2b(xv.z + b2f(a.z) * m.z + b2f(c.z));
        unsigned short u3 = f2b(xv.w + b2f(a.w) * m.w + b2f(c.w));
        *(uint2*)(x_mid + base) = make_uint2(
            (unsigned int)u0 | ((unsigned int)u1 << 16),
            (unsigned int)u2 | ((unsigned int)u3 << 16));
        v[0] = b2f(u0); v[1] = b2f(u1); v[2] = b2f(u2); v[3] = b2f(u3);
    }
    float s  = v[0] + v[1] + v[2] + v[3];
    float sq = v[0]*v[0] + v[1]*v[1] + v[2]*v[2] + v[3]*v[3];
    #pragma unroll
    for (int off = 32; off > 0; off >>= 1) {
        s  += __shfl_xor(s, off);
        sq += __shfl_xor(sq, off);
    }
    float mean = s * (1.f / CH);
    float var  = sq * (1.f / CH) - mean * mean;
    float rstd = rsqrtf(var + 1e-5f);
    if (act) {
        float4 gg = *(const float4*)&g[lane * 4];
        float4 bb = *(const float4*)&bta[lane * 4];
        unsigned int o0 = (unsigned int)f2b((v[0]-mean)*rstd*gg.x + bb.x)
                        | ((unsigned int)f2b((v[1]-mean)*rstd*gg.y + bb.y) << 16);
        unsigned int o1 = (unsigned int)f2b((v[2]-mean)*rstd*gg.z + bb.z)
                        | ((unsigned int)f2b((v[3]-mean)*rstd*gg.w + bb.w) << 16);
        *(uint2*)(n2 + (size_t)tok * CH + lane * 4) = make_uint2(o0, o1);
    }
}

// ---------------- launch ----------------
extern "C" void kernel_launch(void* const* d_in, const int* in_sizes, int n_in,
                              void* d_out, int out_size, void* d_ws, size_t ws_size,
                              hipStream_t stream)
{
    const float* x       = (const float*)d_in[0];
    const float* w_qkv   = (const float*)d_in[1];
    const float* b_rel   = (const float*)d_in[2];
    const float* w_proj  = (const float*)d_in[3];
    const float* b_proj  = (const float*)d_in[4];
    const float* conv_dw = (const float*)d_in[5];
    const float* cg_w1   = (const float*)d_in[6];
    const float* cg_w2   = (const float*)d_in[7];
    const float* ffn_w1  = (const float*)d_in[8];
    const float* ffn_dw  = (const float*)d_in[9];
    const float* ffn_w2  = (const float*)d_in[10];
    const float* n1_g    = (const float*)d_in[11];
    const float* n1_b    = (const float*)d_in[12];
    const float* n2_g    = (const float*)d_in[13];
    const float* n2_b    = (const float*)d_in[14];

    // ---- workspace layout (bytes), peak ~225.6 MiB ----
    // [0,47.2): n1, then x_mid (n1 dead after qkvattn+dwconv1)
    // [47.2,94.4): attn_out (window-ordered)
    // [94.4,141.6): attn_feat
    // [47.2,141.6): h (attn_out dead after proj, attn_feat dead after resid)
    // [141.6,188.7): n2 ; [141.6,235.9): h_s (n2 dead after ffn1)
    // [188.7,235.9): conv_feat (dead after resid)
    char* ws = (char*)d_ws;
    unsigned short* n1        = (unsigned short*)(ws);
    unsigned short* x_mid     = (unsigned short*)(ws);
    unsigned short* attn_out  = (unsigned short*)(ws + 47185920);
    unsigned short* attn_feat = (unsigned short*)(ws + 94371840);
    unsigned short* h         = (unsigned short*)(ws + 47185920);
    unsigned short* n2        = (unsigned short*)(ws + 141557760);
    unsigned short* h_s       = (unsigned short*)(ws + 141557760);
    unsigned short* conv_feat = (unsigned short*)(ws + 188743680);
    float*          pooled    = (float*)(ws + 235929600);                   // 1440 B
    float*          cmv       = (float*)(ws + 235931040);                   // 1440 B
    unsigned short* wbf       = (unsigned short*)(ws + 235932480);          // 518,400 B
    float*          wT1       = (float*)(ws + 236450880);                   // 25,920 B
    float*          wT2       = (float*)(ws + 236476800);                   // 51,840 B
    unsigned short* br4       = (unsigned short*)(ws + 236528640);          // 49,152 B
    unsigned short* wqkv_b  = wbf;
    unsigned short* wproj_b = wbf + 97200;
    unsigned short* wffn1_b = wbf + 129600;
    unsigned short* wffn2_b = wbf + 194400;
    float* out = (float*)d_out;

    hipMemsetAsync(pooled, 0, 2880, stream);

    // 0. weight prep (incl. per-thread-ordered bf16 b_rel)
    convw_kernel<<<1185, 256, 0, stream>>>(w_qkv, w_proj, ffn_w1, ffn_w2,
                                           conv_dw, ffn_dw, b_rel, wbf, wT1, wT2, br4);
    // 1. LN1: x(fp32) -> n1(bf16)
    ln_kernel<float><<<BL / 4, 256, 0, stream>>>(x, n1_g, n1_b, n1);
    // 2. FUSED qkv + window attention: n1 -> attn_out (window-ordered)
    qkvattn_kernel<<<2048, 256, 0, stream>>>(n1, wqkv_b, br4, attn_out);
    // 3. conv branch: gelu(dwconv3x3(n1)) -> conv_feat
    dwconv_kernel<CH, true><<<1472, 256, 0, stream>>>(n1, wT1, conv_feat);
    // 4. pooled = sum_L conv_feat
    pool_kernel<<<BATCH * 128, 64, 0, stream>>>(conv_feat, pooled);
    // 5. cm
    cm_kernel<<<1, 256, 0, stream>>>(pooled, cg_w1, cg_w2, cmv);
    // 6. attn_feat = attn_out @ w_proj^T + b_proj; X window-ordered, Y token order (PERM=2)
    gemm_kernel<180, 0, true, false, 2, unsigned short><<<BL / 128, 256, 0, stream>>>(
        attn_out, CH, wproj_b, b_proj, nullptr, 0, attn_feat, CH, CH);
    // 7. x_mid = x + attn_feat*cm + conv_feat (bf16) ; n2 = LN2(x_mid)  [fused]
    resid_ln2_kernel<<<BL / 4, 256, 0, stream>>>(x, attn_feat, conv_feat, cmv,
                                                 n2_g, n2_b, x_mid, n2);
    // 8. h = gelu(n2 @ ffn_w1^T)
    gemm_kernel<180, 1, false, false, 0, unsigned short><<<BL / 128, 256, 0, stream>>>(
        n2, CH, wffn1_b, nullptr, nullptr, 0, h, HDF, HDF);
    // 9. h_s = dwconv3x3(h)
    dwconv_kernel<HDF, false><<<2880, 256, 0, stream>>>(h, wT2, h_s);
    // 10. out(fp32) = x_mid + h_s @ ffn_w2^T
    gemm_kernel<360, 0, false, true, 0, float><<<BL / 128, 256, 0, stream>>>(
        h_s, HDF, wffn2_b, nullptr, x_mid, CH, out, CH, CH);
}